// Round 15
// baseline (766.176 us; speedup 1.0000x reference)
//
#include <hip/hip_runtime.h>
#include <math.h>
#include <cstddef>

#define N_NODES 32768
#define C_DIM   128
#define E_EDGES 262144
#define B_GR    64
#define NPG     512
#define WALK_D  20
#define L_LAYERS 4

static constexpr int NF = N_NODES * C_DIM;  // 4,194,304 floats per [N,C] tensor

typedef __attribute__((ext_vector_type(8))) short bf16x8;
typedef __attribute__((ext_vector_type(4))) float f32x4;
typedef __attribute__((ext_vector_type(4))) short short4v;

__device__ inline unsigned short f2bf(float f)
{
    union { float f; unsigned u; } v; v.f = f;
    unsigned r = v.u + 0x7fff + ((v.u >> 16) & 1);
    return (unsigned short)(r >> 16);
}
__device__ inline float bf2f_lo(unsigned u) { return __uint_as_float(u << 16); }
__device__ inline float bf2f_hi(unsigned u) { return __uint_as_float(u & 0xffff0000u); }
// HW packed bf16 convert (RNE, identical bits to f2bf for normal/denormal finite inputs)
__device__ inline unsigned cvt_pk_bf16(float lo, float hi)
{
    unsigned r;
    asm("v_cvt_pk_bf16_f32 %0, %1, %2" : "=v"(r) : "v"(lo), "v"(hi));
    return r;
}

// ---------------- PE batch-norm statistics: register-private + wave reduce ----------------
__global__ __launch_bounds__(256) void pe_stats_k(const float* __restrict__ pe, float* __restrict__ acc)
{
    int gt = blockIdx.x * 256 + threadIdx.x;   // 8192 threads, 4 rows each
    float s[WALK_D], q[WALK_D];
    #pragma unroll
    for (int c = 0; c < WALK_D; ++c) { s[c] = 0.f; q[c] = 0.f; }
    for (int r = 0; r < 4; ++r) {
        const float* row = &pe[(size_t)(gt + r * 8192) * WALK_D];
        float v[20];
        #pragma unroll
        for (int j = 0; j < 5; ++j) *(float4*)&v[j * 4] = *(const float4*)(row + j * 4);
        #pragma unroll
        for (int c = 0; c < WALK_D; ++c) { s[c] += v[c]; q[c] += v[c] * v[c]; }
    }
    #pragma unroll
    for (int c = 0; c < WALK_D; ++c) {
        float ss = s[c], qq = q[c];
        #pragma unroll
        for (int m = 1; m < 64; m <<= 1) { ss += __shfl_xor(ss, m); qq += __shfl_xor(qq, m); }
        if ((threadIdx.x & 63) == 0) { atomicAdd(&acc[c], ss); atomicAdd(&acc[32 + c], qq); }
    }
}

// ---------------- initial embedding h0 = [node_emb[x], BN(pe) @ pe_lin]; pe_fin folded in ----------------
__global__ __launch_bounds__(256) void h0_k(const int* __restrict__ x, const float* __restrict__ pe,
    const float* __restrict__ node_emb, const float* __restrict__ plw, const float* __restrict__ plb,
    const float* __restrict__ peacc, const float* __restrict__ pe_g, const float* __restrict__ pe_b,
    float* __restrict__ h, unsigned short* __restrict__ h16)
{
    __shared__ float spe[64];
    int tid = threadIdx.x;
    if (tid < WALK_D) {
        float mean = peacc[tid] * (1.f / N_NODES);
        float var  = peacc[32 + tid] * (1.f / N_NODES) - mean * mean;
        float sc   = pe_g[tid] * rsqrtf(var + 1e-5f);
        spe[tid] = sc;
        spe[32 + tid] = pe_b[tid] - mean * sc;
    }
    __syncthreads();
    int i = blockIdx.x * 2 + (tid >> 7);
    int c = tid & 127;
    float v;
    if (c < 120) {
        v = node_emb[x[i] * 120 + c];
    } else {
        int pc = c - 120;
        v = plb[pc];
        #pragma unroll
        for (int k = 0; k < WALK_D; ++k) {
            float pn = pe[i * WALK_D + k] * spe[k] + spe[32 + k];
            v = fmaf(pn, plw[k * 8 + pc], v);
        }
    }
    h[i * C_DIM + c] = v;
    h16[i * C_DIM + c] = f2bf(v);
}

// ---------------- CSR build (by destination) ----------------
__global__ __launch_bounds__(256) void hist_k(const int* __restrict__ dst, int* __restrict__ cnt)
{
    int e = blockIdx.x * 256 + threadIdx.x;
    atomicAdd(&cnt[dst[e]], 1);
}

__global__ __launch_bounds__(256) void bsum_k(const int* __restrict__ cnt, int* __restrict__ bsum)
{
    __shared__ int ws[4];
    int b = blockIdx.x, t = threadIdx.x;
    int v = cnt[b * 256 + t];
    #pragma unroll
    for (int m = 1; m < 64; m <<= 1) v += __shfl_xor(v, m);
    if ((t & 63) == 0) ws[t >> 6] = v;
    __syncthreads();
    if (t == 0) bsum[b] = ws[0] + ws[1] + ws[2] + ws[3];
}

__global__ __launch_bounds__(128) void bscan_k(const int* __restrict__ bsum, int* __restrict__ bpre)
{
    __shared__ int s[128];
    int t = threadIdx.x;
    int v = bsum[t];
    s[t] = v;
    __syncthreads();
    for (int off = 1; off < 128; off <<= 1) {
        int u = (t >= off) ? s[t - off] : 0;
        __syncthreads();
        s[t] += u;
        __syncthreads();
    }
    bpre[t] = s[t] - v;
}

__global__ __launch_bounds__(256) void indptr_k(const int* __restrict__ cnt, const int* __restrict__ bpre,
                                                int* __restrict__ indptr)
{
    __shared__ int s[256];
    int b = blockIdx.x, t = threadIdx.x;
    int v = cnt[b * 256 + t];
    s[t] = v;
    __syncthreads();
    for (int off = 1; off < 256; off <<= 1) {
        int u = (t >= off) ? s[t - off] : 0;
        __syncthreads();
        s[t] += u;
        __syncthreads();
    }
    indptr[b * 256 + t] = bpre[b] + s[t] - v;
    if (b == 127 && t == 255) indptr[N_NODES] = E_EDGES;
}

// ---------------- scatter + edge-record build: esa[pos] = src | attr<<16 ----------------
__global__ __launch_bounds__(256) void scatter_k(const int* __restrict__ dst, const int* __restrict__ src,
                                                 const int* __restrict__ attr, const int* __restrict__ indptr,
                                                 int* __restrict__ cur, int* __restrict__ esa)
{
    int e = blockIdx.x * 256 + threadIdx.x;
    int d = dst[e];
    int pos = atomicAdd(&cur[d], 1);
    esa[indptr[d] + pos] = src[e] | (attr[e] << 16);
}

// ---------------- weight prep: W[K][N] f32 -> Wt[N][K] bf16, all 24 matrices ----------------
__global__ __launch_bounds__(256) void wt_prep_k(
    const float* __restrict__ gw1, const float* __restrict__ gw2,
    const float* __restrict__ wqkv, const float* __restrict__ wo,
    const float* __restrict__ fw1, const float* __restrict__ fw2,
    short* __restrict__ out)
{
    __shared__ float ts[32][36];
    int b = blockIdx.x;
    int l = b / 160, t = b % 160;
    const float* src; int K, N; size_t obase; int tile;
    if (t < 16)       { src = gw1  + (size_t)l * 16384; K = 128; N = 128; obase = (size_t)l * 163840 + 0;      tile = t; }
    else if (t < 32)  { src = gw2  + (size_t)l * 16384; K = 128; N = 128; obase = (size_t)l * 163840 + 16384;  tile = t - 16; }
    else if (t < 80)  { src = wqkv + (size_t)l * 49152; K = 128; N = 384; obase = (size_t)l * 163840 + 32768;  tile = t - 32; }
    else if (t < 96)  { src = wo   + (size_t)l * 16384; K = 128; N = 128; obase = (size_t)l * 163840 + 81920;  tile = t - 80; }
    else if (t < 128) { src = fw1  + (size_t)l * 32768; K = 128; N = 256; obase = (size_t)l * 163840 + 98304;  tile = t - 96; }
    else              { src = fw2  + (size_t)l * 32768; K = 256; N = 128; obase = (size_t)l * 163840 + 131072; tile = t - 128; }
    int ntN = N / 32;
    int tk = tile / ntN, tn = tile % ntN;
    int tid = threadIdx.x;
    int r = tid >> 3, c4 = (tid & 7) * 4;
    *(float4*)&ts[r][c4] = *(const float4*)&src[(size_t)(tk * 32 + r) * N + tn * 32 + c4];
    __syncthreads();
    int n = tid >> 3, k4 = (tid & 7) * 4;
    short4v pk;
    #pragma unroll
    for (int i2 = 0; i2 < 4; ++i2) pk[i2] = (short)f2bf(ts[k4 + i2][n]);
    *(short4v*)&out[obase + (size_t)(tn * 32 + n) * K + tk * 32 + k4] = pk;
}

// ---------------- merged gather + qkv GEMM (independent chains, one dispatch) ----------------
// Blocks [0,768): qkv mgemm (ABF, OUTBF, VOUT) — identical arithmetic to mgemm_k.
// Blocks [768,8960): GINE gather — identical arithmetic to the standalone gather.
__global__ __launch_bounds__(256) void gq_k(
    const unsigned short* __restrict__ h16,
    const int* __restrict__ esa, const int* __restrict__ indptr,
    const float* __restrict__ edge_emb, unsigned short* __restrict__ z16,
    const unsigned short* __restrict__ Bt, const float* __restrict__ bias,
    unsigned short* __restrict__ qkvb, unsigned short* __restrict__ vtg)
{
    __shared__ char smem[49152];
    const int tid = threadIdx.x;
    if (blockIdx.x < 768) {
        short* As = (short*)smem;            // [128 rows][128 k] swizzled (32KB)
        short* Bs = (short*)(smem + 32768);  // [64 cols][128 k] (16KB)
        const int w = tid >> 6;
        const int lane = tid & 63;
        const int lr = lane & 15, lg = lane >> 4;
        const int col0 = (blockIdx.x % 3) * 128;
        const int row0 = (blockIdx.x / 3) * 128;
        const f32x4 zero = {0.f, 0.f, 0.f, 0.f};
        f32x4 acc[2][8];
        #pragma unroll
        for (int i = 0; i < 2; ++i)
            #pragma unroll
            for (int cf = 0; cf < 8; ++cf) acc[i][cf] = zero;

        #pragma unroll
        for (int it = 0; it < 8; ++it) {
            int gid = it * 256 + tid;
            int row = gid >> 4, g = gid & 15;
            bf16x8 pk = *(const bf16x8*)&h16[(size_t)(row0 + row) * 128 + g * 8];
            *(bf16x8*)&As[(row * 16 + (g ^ (row & 7))) * 8] = pk;
        }
        #pragma unroll
        for (int h = 0; h < 2; ++h) {
            if (h > 0) __syncthreads();
            #pragma unroll
            for (int it = 0; it < 4; ++it) {
                int gid = it * 256 + tid;
                int row = gid >> 4, g = gid & 15;
                bf16x8 bv = *(const bf16x8*)&Bt[(size_t)(col0 + h * 64 + row) * 128 + g * 8];
                *(bf16x8*)&Bs[(row * 16 + (g ^ (row & 7))) * 8] = bv;
            }
            __syncthreads();
            #pragma unroll
            for (int ks = 0; ks < 4; ++ks) {
                bf16x8 af[2], bfr[4];
                #pragma unroll
                for (int i = 0; i < 2; ++i) {
                    int row = w * 32 + i * 16 + lr;
                    int g = ks * 4 + lg;
                    af[i] = *(const bf16x8*)&As[(row * 16 + (g ^ (row & 7))) * 8];
                }
                #pragma unroll
                for (int cfl = 0; cfl < 4; ++cfl) {
                    int lc = cfl * 16 + lr;
                    int g = ks * 4 + lg;
                    bfr[cfl] = *(const bf16x8*)&Bs[(lc * 16 + (g ^ (lc & 7))) * 8];
                }
                #pragma unroll
                for (int i = 0; i < 2; ++i)
                    #pragma unroll
                    for (int cfl = 0; cfl < 4; ++cfl)
                        acc[i][h * 4 + cfl] = __builtin_amdgcn_mfma_f32_16x16x32_bf16(af[i], bfr[cfl], acc[i][h * 4 + cfl], 0, 0, 0);
            }
        }
        float bs_v[8];
        #pragma unroll
        for (int cf = 0; cf < 8; ++cf) bs_v[cf] = bias[col0 + cf * 16 + lr];
        const bool vblk = (col0 == 256);
        #pragma unroll
        for (int i = 0; i < 2; ++i) {
            #pragma unroll
            for (int r = 0; r < 4; ++r) {
                size_t grow = row0 + w * 32 + i * 16 + lg * 4 + r;
                #pragma unroll
                for (int cf = 0; cf < 8; ++cf) {
                    int c = col0 + cf * 16 + lr;
                    float val = acc[i][cf][r] + bs_v[cf];
                    if (vblk) {
                        int g2 = (int)(grow >> 9);
                        int key = (int)(grow & 511);
                        int kc = key >> 6, kg = (key >> 3) & 7, j = key & 7;
                        int cd = c - 256;
                        int hd2 = cd >> 5, dd = cd & 31;
                        vtg[((size_t)(g2 * 4 + hd2) * 8 + kc) * 2048 + dd * 64 + ((kg ^ (dd & 7)) << 3) + j] = f2bf(val);
                    } else {
                        qkvb[grow * 384 + c] = f2bf(val);
                    }
                }
            }
        }
    } else {
        float* ee = (float*)smem;
        ee[tid] = edge_emb[tid];
        ee[tid + 256] = edge_emb[tid + 256];
        __syncthreads();
        int i = (blockIdx.x - 768) * 4 + (tid >> 6);
        int c = (tid & 63) * 2;
        int p0 = indptr[i], p1 = indptr[i + 1];
        float s0 = 0.f, s1 = 0.f;
        int p = p0;
        for (; p + 4 <= p1; p += 4) {
            int sa0 = esa[p], sa1 = esa[p + 1], sa2 = esa[p + 2], sa3 = esa[p + 3];
            unsigned u0 = *(const unsigned*)&h16[(size_t)(sa0 & 0xffff) * C_DIM + c];
            unsigned u1 = *(const unsigned*)&h16[(size_t)(sa1 & 0xffff) * C_DIM + c];
            unsigned u2 = *(const unsigned*)&h16[(size_t)(sa2 & 0xffff) * C_DIM + c];
            unsigned u3 = *(const unsigned*)&h16[(size_t)(sa3 & 0xffff) * C_DIM + c];
            float2 e0 = *(const float2*)&ee[(sa0 >> 16) * C_DIM + c];
            float2 e1 = *(const float2*)&ee[(sa1 >> 16) * C_DIM + c];
            float2 e2 = *(const float2*)&ee[(sa2 >> 16) * C_DIM + c];
            float2 e3 = *(const float2*)&ee[(sa3 >> 16) * C_DIM + c];
            s0 += fmaxf(bf2f_lo(u0) + e0.x, 0.f); s1 += fmaxf(bf2f_hi(u0) + e0.y, 0.f);
            s0 += fmaxf(bf2f_lo(u1) + e1.x, 0.f); s1 += fmaxf(bf2f_hi(u1) + e1.y, 0.f);
            s0 += fmaxf(bf2f_lo(u2) + e2.x, 0.f); s1 += fmaxf(bf2f_hi(u2) + e2.y, 0.f);
            s0 += fmaxf(bf2f_lo(u3) + e3.x, 0.f); s1 += fmaxf(bf2f_hi(u3) + e3.y, 0.f);
        }
        for (; p < p1; ++p) {
            int sa = esa[p];
            unsigned u = *(const unsigned*)&h16[(size_t)(sa & 0xffff) * C_DIM + c];
            float2 ev = *(const float2*)&ee[(sa >> 16) * C_DIM + c];
            s0 += fmaxf(bf2f_lo(u) + ev.x, 0.f);
            s1 += fmaxf(bf2f_hi(u) + ev.y, 0.f);
        }
        unsigned us = *(const unsigned*)&h16[(size_t)i * C_DIM + c];
        s0 += bf2f_lo(us);
        s1 += bf2f_hi(us);
        *(unsigned*)&z16[(size_t)i * C_DIM + c] = cvt_pk_bf16(s0, s1);
    }
}

// ---------------- MFMA bf16 GEMM (B staged in 64-col halves; 48KB LDS -> 3 blocks/CU) ----------------
template<int KD, int NC, int AMODE, int RESMODE, bool RELU, bool STATS, bool OUTBF, bool ABF, bool VOUT>
__global__ __launch_bounds__(256) void mgemm_k(
    const void* __restrict__ Av, const float* __restrict__ A2,
    const float* __restrict__ affA1, const float* __restrict__ affA2,
    const unsigned short* __restrict__ Bt, const float* __restrict__ bias,
    const float* __restrict__ R1, const float* __restrict__ R2,
    const float* __restrict__ affR1, const float* __restrict__ affR2,
    void* __restrict__ Cout, float* __restrict__ stats,
    unsigned short* __restrict__ vtg)
{
    __shared__ short As[16384];   // [128 rows][128 k] bf16, XOR-swizzled granules
    __shared__ short Bs[8192];    // [64 cols][128 k] bf16 (current half)
    const int tid = threadIdx.x;
    const int w = tid >> 6;
    const int lane = tid & 63;
    const int lr = lane & 15, lg = lane >> 4;
    const int row0 = blockIdx.y * 128;
    const int col0 = blockIdx.x * 128;

    const f32x4 zero = {0.f, 0.f, 0.f, 0.f};
    f32x4 acc[2][8];
    #pragma unroll
    for (int i = 0; i < 2; ++i)
        #pragma unroll
        for (int cf = 0; cf < 8; ++cf) acc[i][cf] = zero;

    for (int kt = 0; kt < KD / 128; ++kt) {
        if (kt > 0) __syncthreads();
        #pragma unroll
        for (int it = 0; it < 8; ++it) {
            int gid = it * 256 + tid;
            int row = gid >> 4, g = gid & 15;
            bf16x8 pk;
            if (ABF) {
                pk = *(const bf16x8*)&((const unsigned short*)Av)[(size_t)(row0 + row) * KD + kt * 128 + g * 8];
            } else {
                const float* Af = (const float*)Av;
                const float* ap = &Af[(size_t)(row0 + row) * KD + kt * 128 + g * 8];
                float v[8];
                *(float4*)&v[0] = *(const float4*)ap;
                *(float4*)&v[4] = *(const float4*)(ap + 4);
                if (AMODE == 1) {
                    const float* ap2 = &A2[(size_t)(row0 + row) * KD + kt * 128 + g * 8];
                    float u[8];
                    *(float4*)&u[0] = *(const float4*)ap2;
                    *(float4*)&u[4] = *(const float4*)(ap2 + 4);
                    #pragma unroll
                    for (int j = 0; j < 8; ++j) {
                        int ck = g * 8 + j;
                        v[j] = v[j] * affA1[ck] + affA1[128 + ck] + u[j] * affA2[ck] + affA2[128 + ck];
                    }
                }
                #pragma unroll
                for (int j = 0; j < 8; ++j) pk[j] = (short)f2bf(v[j]);
            }
            *(bf16x8*)&As[(row * 16 + (g ^ (row & 7))) * 8] = pk;
        }
        #pragma unroll
        for (int h = 0; h < 2; ++h) {
            if (h > 0) __syncthreads();   // prior Bs reads done
            #pragma unroll
            for (int it = 0; it < 4; ++it) {
                int gid = it * 256 + tid;
                int row = gid >> 4, g = gid & 15;   // row = local B col in half
                bf16x8 bv = *(const bf16x8*)&Bt[(size_t)(col0 + h * 64 + row) * KD + kt * 128 + g * 8];
                *(bf16x8*)&Bs[(row * 16 + (g ^ (row & 7))) * 8] = bv;
            }
            __syncthreads();
            #pragma unroll
            for (int ks = 0; ks < 4; ++ks) {
                bf16x8 af[2], bfr[4];
                #pragma unroll
                for (int i = 0; i < 2; ++i) {
                    int row = w * 32 + i * 16 + lr;
                    int g = ks * 4 + lg;
                    af[i] = *(const bf16x8*)&As[(row * 16 + (g ^ (row & 7))) * 8];
                }
                #pragma unroll
                for (int cfl = 0; cfl < 4; ++cfl) {
                    int lc = cfl * 16 + lr;   // local col in half; (col&7)==(lc&7)
                    int g = ks * 4 + lg;
                    bfr[cfl] = *(const bf16x8*)&Bs[(lc * 16 + (g ^ (lc & 7))) * 8];
                }
                #pragma unroll
                for (int i = 0; i < 2; ++i)
                    #pragma unroll
                    for (int cfl = 0; cfl < 4; ++cfl)
                        acc[i][h * 4 + cfl] = __builtin_amdgcn_mfma_f32_16x16x32_bf16(af[i], bfr[cfl], acc[i][h * 4 + cfl], 0, 0, 0);
            }
        }
    }

    float* cs = (float*)As;       // alias LDS after compute
    float* cq = cs + 128;
    if (STATS) {
        __syncthreads();
        if (tid < 128) { cs[tid] = 0.f; cq[tid] = 0.f; }
        __syncthreads();
    }
    float bs_v[8];
    #pragma unroll
    for (int cf = 0; cf < 8; ++cf) bs_v[cf] = bias[col0 + cf * 16 + lr];
    float rs1[8], ro1[8], rs2[8], ro2[8];
    if (RESMODE == 2) {
        #pragma unroll
        for (int cf = 0; cf < 8; ++cf) {
            int c = cf * 16 + lr;
            rs1[cf] = affR1[c]; ro1[cf] = affR1[128 + c];
            rs2[cf] = affR2[c]; ro2[cf] = affR2[128 + c];
        }
    }
    float colS[8], colQ[8];
    #pragma unroll
    for (int cf = 0; cf < 8; ++cf) { colS[cf] = 0.f; colQ[cf] = 0.f; }
    const bool vblk = VOUT && (col0 == 256);
    #pragma unroll
    for (int i = 0; i < 2; ++i) {
        #pragma unroll
        for (int r = 0; r < 4; ++r) {
            size_t grow = row0 + w * 32 + i * 16 + lg * 4 + r;
            #pragma unroll
            for (int cf = 0; cf < 8; ++cf) {
                int c = col0 + cf * 16 + lr;
                float val = acc[i][cf][r] + bs_v[cf];
                if (RESMODE == 1) val += R1[grow * NC + c];
                if (RESMODE == 2) {
                    val += R1[grow * 128 + c] * rs1[cf] + ro1[cf]
                         + R2[grow * 128 + c] * rs2[cf] + ro2[cf];
                }
                if (RELU) val = fmaxf(val, 0.f);
                if (VOUT && vblk) {
                    int g2 = (int)(grow >> 9);
                    int key = (int)(grow & 511);
                    int kc = key >> 6, kg = (key >> 3) & 7, j = key & 7;
                    int cd = c - 256;
                    int hd2 = cd >> 5, dd = cd & 31;
                    vtg[((size_t)(g2 * 4 + hd2) * 8 + kc) * 2048 + dd * 64 + ((kg ^ (dd & 7)) << 3) + j] = f2bf(val);
                } else if (OUTBF) {
                    ((unsigned short*)Cout)[grow * NC + c] = f2bf(val);
                } else {
                    ((float*)Cout)[grow * NC + c] = val;
                }
                if (STATS) { colS[cf] += val; colQ[cf] += val * val; }
            }
        }
    }
    if (STATS) {
        #pragma unroll
        for (int cf = 0; cf < 8; ++cf) {
            float s = colS[cf], q = colQ[cf];
            s += __shfl_xor(s, 16); s += __shfl_xor(s, 32);
            q += __shfl_xor(q, 16); q += __shfl_xor(q, 32);
            if (lg == 0) { atomicAdd(&cs[cf * 16 + lr], s); atomicAdd(&cq[cf * 16 + lr], q); }
        }
        __syncthreads();
        if (tid < 128) {
            atomicAdd(&stats[tid], cs[tid]);
            atomicAdd(&stats[128 + tid], cq[tid]);
        }
    }
}

// ---------------- fused GINE MLP, 512 threads / 8 waves, 128-row tile ----------------
__global__ __launch_bounds__(512) void gine_mlp_k(
    const unsigned short* __restrict__ z16,
    const unsigned short* __restrict__ W1t, const float* __restrict__ b1,
    const unsigned short* __restrict__ W2t, const float* __restrict__ b2,
    const float* __restrict__ Hres,
    float* __restrict__ T1out, float* __restrict__ stats)
{
    __shared__ short As[16384];
    __shared__ short Bs[16384];
    const int tid = threadIdx.x;
    const int w = tid >> 6;          // 0..7
    const int lane = tid & 63;
    const int lr = lane & 15, lg = lane >> 4;
    const int row0 = blockIdx.x * 128;
    const f32x4 zero = {0.f, 0.f, 0.f, 0.f};
    const int arow = w * 16 + lr;

    #pragma unroll
    for (int it = 0; it < 4; ++it) {
        int gid = it * 512 + tid;
        int row = gid >> 4, g = gid & 15;
        bf16x8 av = *(const bf16x8*)&z16[(size_t)(row0 + row) * 128 + g * 8];
        *(bf16x8*)&As[(row * 16 + (g ^ (row & 7))) * 8] = av;
        bf16x8 bv = *(const bf16x8*)&W1t[(size_t)row * 128 + g * 8];
        *(bf16x8*)&Bs[(row * 16 + (g ^ (row & 7))) * 8] = bv;
    }
    __syncthreads();

    f32x4 acc[8];
    #pragma unroll
    for (int cf = 0; cf < 8; ++cf) acc[cf] = zero;
    #pragma unroll
    for (int ks = 0; ks < 4; ++ks) {
        int g = ks * 4 + lg;
        bf16x8 af = *(const bf16x8*)&As[(arow * 16 + (g ^ (arow & 7))) * 8];
        #pragma unroll
        for (int cf = 0; cf < 8; ++cf) {
            int c = cf * 16 + lr;
            bf16x8 bfr = *(const bf16x8*)&Bs[(c * 16 + (g ^ (c & 7))) * 8];
            acc[cf] = __builtin_amdgcn_mfma_f32_16x16x32_bf16(af, bfr, acc[cf], 0, 0, 0);
        }
    }
    __syncthreads();   // all As(z)/Bs(W1) reads complete

    {   // Y = f2bf(relu(acc + b1)) -> As (same swizzled positions & rounding point)
        float bias1[8];
        #pragma unroll
        for (int cf = 0; cf < 8; ++cf) bias1[cf] = b1[cf * 16 + lr];
        #pragma unroll
        for (int r = 0; r < 4; ++r) {
            int row = w * 16 + lg * 4 + r;
            #pragma unroll
            for (int cf = 0; cf < 8; ++cf) {
                int col = cf * 16 + lr;
                float val = fmaxf(acc[cf][r] + bias1[cf], 0.f);
                As[(row * 16 + ((col >> 3) ^ (row & 7))) * 8 + (col & 7)] = (short)f2bf(val);
            }
        }
    }
    #pragma unroll
    for (int it = 0; it < 4; ++it) {
        int gid = it * 512 + tid;
        int row = gid >> 4, g = gid & 15;
        bf16x8 bv = *(const bf16x8*)&W2t[(size_t)row * 128 + g * 8];
        *(bf16x8*)&Bs[(row * 16 + (g ^ (row & 7))) * 8] = bv;
    }
    __syncthreads();

    #pragma unroll
    for (int cf = 0; cf < 8; ++cf) acc[cf] = zero;
    #pragma unroll
    for (int ks = 0; ks < 4; ++ks) {
        int g = ks * 4 + lg;
        bf16x8 af = *(const bf16x8*)&As[(arow * 16 + (g ^ (arow & 7))) * 8];
        #pragma unroll
        for (int cf = 0; cf < 8; ++cf) {
            int c = cf * 16 + lr;
            bf16x8 bfr = *(const bf16x8*)&Bs[(c * 16 + (g ^ (c & 7))) * 8];
            acc[cf] = __builtin_amdgcn_mfma_f32_16x16x32_bf16(af, bfr, acc[cf], 0, 0, 0);
        }
    }

    float* cs = (float*)As;
    float* cq = cs + 128;
    __syncthreads();
    if (tid < 128) { cs[tid] = 0.f; cq[tid] = 0.f; }
    __syncthreads();
    float bs_v[8];
    #pragma unroll
    for (int cf = 0; cf < 8; ++cf) bs_v[cf] = b2[cf * 16 + lr];
    float colS[8], colQ[8];
    #pragma unroll
    for (int cf = 0; cf < 8; ++cf) { colS[cf] = 0.f; colQ[cf] = 0.f; }
    #pragma unroll
    for (int r = 0; r < 4; ++r) {
        size_t grow = row0 + w * 16 + lg * 4 + r;
        #pragma unroll
        for (int cf = 0; cf < 8; ++cf) {
            int c = cf * 16 + lr;
            float val = acc[cf][r] + bs_v[cf] + Hres[grow * 128 + c];
            T1out[grow * 128 + c] = val;
            colS[cf] += val; colQ[cf] += val * val;
        }
    }
    #pragma unroll
    for (int cf = 0; cf < 8; ++cf) {
        float s = colS[cf], q = colQ[cf];
        s += __shfl_xor(s, 16); s += __shfl_xor(s, 32);
        q += __shfl_xor(q, 16); q += __shfl_xor(q, 32);
        if (lg == 0) { atomicAdd(&cs[cf * 16 + lr], s); atomicAdd(&cq[cf * 16 + lr], q); }
    }
    __syncthreads();
    if (tid < 128) {
        atomicAdd(&stats[tid], cs[tid]);
        atomicAdd(&stats[128 + tid], cq[tid]);
    }
}

// ---------------- fused FFN (+ BN1/BN2 finalize in prologue): T1 = FFN(...) + aff(T1,T2), BN3 stats ----
__global__ __launch_bounds__(256) void ffn_mlp_k(
    const float* __restrict__ T1, const float* __restrict__ T2,
    const float* __restrict__ a1, const float* __restrict__ g1v, const float* __restrict__ b1v,
    const float* __restrict__ a2, const float* __restrict__ g2v, const float* __restrict__ b2v,
    const unsigned short* __restrict__ W1t, const float* __restrict__ fb1,
    const unsigned short* __restrict__ W2t, const float* __restrict__ fb2,
    float* __restrict__ T1out, float* __restrict__ stats)
{
    __shared__ short As[8192];    // [64 rows][128 k]
    __shared__ short Bs[16384];   // [128][128] (W1 col-half / W2 k-half)
    __shared__ short Ys[8192];    // [64 rows][128 hidden] current half
    __shared__ float sf1l[256], sf2l[256];
    const int tid = threadIdx.x;
    const int w = tid >> 6;
    const int lane = tid & 63;
    const int lr = lane & 15, lg = lane >> 4;
    const int row0 = blockIdx.x * 64;
    const f32x4 zero = {0.f, 0.f, 0.f, 0.f};

    if (tid < 128) {   // BN1/BN2 finalize (identical formula to the old bn_fin_k)
        float mean = a1[tid] * (1.f / N_NODES);
        float var  = a1[128 + tid] * (1.f / N_NODES) - mean * mean;
        float sc   = g1v[tid] * rsqrtf(var + 1e-5f);
        sf1l[tid] = sc; sf1l[128 + tid] = b1v[tid] - mean * sc;
        mean = a2[tid] * (1.f / N_NODES);
        var  = a2[128 + tid] * (1.f / N_NODES) - mean * mean;
        sc   = g2v[tid] * rsqrtf(var + 1e-5f);
        sf2l[tid] = sc; sf2l[128 + tid] = b2v[tid] - mean * sc;
    }
    __syncthreads();

    #pragma unroll
    for (int it = 0; it < 4; ++it) {
        int gid = it * 256 + tid;
        int row = gid >> 4, g = gid & 15;
        const float* ap = &T1[(size_t)(row0 + row) * 128 + g * 8];
        const float* ap2 = &T2[(size_t)(row0 + row) * 128 + g * 8];
        float v[8], u[8];
        *(float4*)&v[0] = *(const float4*)ap;
        *(float4*)&v[4] = *(const float4*)(ap + 4);
        *(float4*)&u[0] = *(const float4*)ap2;
        *(float4*)&u[4] = *(const float4*)(ap2 + 4);
        unsigned pw[4];
        #pragma unroll
        for (int j2 = 0; j2 < 4; ++j2) {
            int ck0 = g * 8 + j2 * 2, ck1 = ck0 + 1;
            float x0 = v[j2 * 2]     * sf1l[ck0] + sf1l[128 + ck0] + u[j2 * 2]     * sf2l[ck0] + sf2l[128 + ck0];
            float x1 = v[j2 * 2 + 1] * sf1l[ck1] + sf1l[128 + ck1] + u[j2 * 2 + 1] * sf2l[ck1] + sf2l[128 + ck1];
            pw[j2] = cvt_pk_bf16(x0, x1);
        }
        *(uint4*)&As[(row * 16 + (g ^ (row & 7))) * 8] = *(uint4*)pw;
    }

    f32x4 acc2[8];
    #pragma unroll
    for (int cf = 0; cf < 8; ++cf) acc2[cf] = zero;

    const int arow = w * 16 + lr;
    for (int h = 0; h < 2; ++h) {
        if (h > 0) __syncthreads();
        #pragma unroll
        for (int it = 0; it < 8; ++it) {
            int gid = it * 256 + tid;
            int row = gid >> 4, g = gid & 15;
            bf16x8 bv = *(const bf16x8*)&W1t[(size_t)(h * 128 + row) * 128 + g * 8];
            *(bf16x8*)&Bs[(row * 16 + (g ^ (row & 7))) * 8] = bv;
        }
        __syncthreads();
        f32x4 accY[8];
        #pragma unroll
        for (int cf = 0; cf < 8; ++cf) accY[cf] = zero;
        #pragma unroll
        for (int ks = 0; ks < 4; ++ks) {
            int g = ks * 4 + lg;
            bf16x8 af = *(const bf16x8*)&As[(arow * 16 + (g ^ (arow & 7))) * 8];
            #pragma unroll
            for (int cf = 0; cf < 8; ++cf) {
                int c = cf * 16 + lr;
                bf16x8 bfr = *(const bf16x8*)&Bs[(c * 16 + (g ^ (c & 7))) * 8];
                accY[cf] = __builtin_amdgcn_mfma_f32_16x16x32_bf16(af, bfr, accY[cf], 0, 0, 0);
            }
        }
        __syncthreads();
        #pragma unroll
        for (int r = 0; r < 4; ++r) {
            int row = w * 16 + lg * 4 + r;
            #pragma unroll
            for (int cf = 0; cf < 8; ++cf) {
                int col = cf * 16 + lr;
                float val = fmaxf(accY[cf][r] + fb1[h * 128 + col], 0.f);
                Ys[(row * 16 + ((col >> 3) ^ (row & 7))) * 8 + (col & 7)] = (short)f2bf(val);
            }
        }
        #pragma unroll
        for (int it = 0; it < 8; ++it) {
            int gid = it * 256 + tid;
            int row = gid >> 4, g = gid & 15;
            bf16x8 bv = *(const bf16x8*)&W2t[(size_t)row * 256 + h * 128 + g * 8];
            *(bf16x8*)&Bs[(row * 16 + (g ^ (row & 7))) * 8] = bv;
        }
        __syncthreads();
        #pragma unroll
        for (int ks = 0; ks < 4; ++ks) {
            int g = ks * 4 + lg;
            bf16x8 af = *(const bf16x8*)&Ys[(arow * 16 + (g ^ (arow & 7))) * 8];
            #pragma unroll
            for (int cf = 0; cf < 8; ++cf) {
                int c = cf * 16 + lr;
                bf16x8 bfr = *(const bf16x8*)&Bs[(c * 16 + (g ^ (c & 7))) * 8];
                acc2[cf] = __builtin_amdgcn_mfma_f32_16x16x32_bf16(af, bfr, acc2[cf], 0, 0, 0);
            }
        }
    }

    float* cs = (float*)As;
    float* cq = cs + 128;
    __syncthreads();
    if (tid < 128) { cs[tid] = 0.f; cq[tid] = 0.f; }
    __syncthreads();
    float bs_v[8], rs1[8], ro1[8], rs2[8], ro2[8];
    #pragma unroll
    for (int cf = 0; cf < 8; ++cf) {
        int c = cf * 16 + lr;
        bs_v[cf] = fb2[c];
        rs1[cf] = sf1l[c]; ro1[cf] = sf1l[128 + c];
        rs2[cf] = sf2l[c]; ro2[cf] = sf2l[128 + c];
    }
    float colS[8], colQ[8];
    #pragma unroll
    for (int cf = 0; cf < 8; ++cf) { colS[cf] = 0.f; colQ[cf] = 0.f; }
    #pragma unroll
    for (int r = 0; r < 4; ++r) {
        size_t grow = row0 + w * 16 + lg * 4 + r;
        #pragma unroll
        for (int cf = 0; cf < 8; ++cf) {
            int c = cf * 16 + lr;
            float val = acc2[cf][r] + bs_v[cf]
                      + T1[grow * 128 + c] * rs1[cf] + ro1[cf]
                      + T2[grow * 128 + c] * rs2[cf] + ro2[cf];
            T1out[grow * 128 + c] = val;
            colS[cf] += val; colQ[cf] += val * val;
        }
    }
    #pragma unroll
    for (int cf = 0; cf < 8; ++cf) {
        float s = colS[cf], q = colQ[cf];
        s += __shfl_xor(s, 16); s += __shfl_xor(s, 32);
        q += __shfl_xor(q, 16); q += __shfl_xor(q, 32);
        if (lg == 0) { atomicAdd(&cs[cf * 16 + lr], s); atomicAdd(&cq[cf * 16 + lr], q); }
    }
    __syncthreads();
    if (tid < 128) {
        atomicAdd(&stats[tid], cs[tid]);
        atomicAdd(&stats[128 + tid], cq[tid]);
    }
}

// ---------------- MFMA flash attention, swapped-QK core, 64 q/block (bitwise-identical) ----------------
__global__ __launch_bounds__(256) void attn_mfma_k(const unsigned short* __restrict__ qkvb,
                                                   const unsigned short* __restrict__ vtg,
                                                   unsigned short* __restrict__ ao16)
{
    __shared__ short Qs[2048];      // [64 q][4 dg ^swz][8]
    __shared__ short Ks[2][2048];   // [64 k][4 dg ^swz][8], double-buffered
    __shared__ short Vs[2][2048];   // pre-swizzled V^T image, double-buffered
    __shared__ short Ps[4][1024];   // per-wave P^T [16 q][8 kgran ^swz][8]
    const int tid = threadIdx.x;
    const int w = tid >> 6, lane = tid & 63;
    const int lr = lane & 15, lg = lane >> 4;
    const int q0 = blockIdx.x * 64;
    const int hd = blockIdx.y;
    const int base = blockIdx.z * NPG;
    const float SCL = 0.17677669529663687f * 1.44269504089f;  // 1/sqrt(32) * log2(e)
    const f32x4 zero = {0.f, 0.f, 0.f, 0.f};
    const unsigned short* vbase = vtg + (size_t)(blockIdx.z * 4 + hd) * 16384;

    {   // stage Q (64 rows) + chunk 0 of K/V
        int row = tid >> 2, g = tid & 3;
        bf16x8 qv = *(const bf16x8*)&qkvb[(size_t)(base + q0 + row) * 384 + hd * 32 + g * 8];
        *(bf16x8*)&Qs[(row * 4 + (g ^ ((row >> 1) & 3))) * 8] = qv;
        bf16x8 kv = *(const bf16x8*)&qkvb[(size_t)(base + row) * 384 + 128 + hd * 32 + g * 8];
        *(bf16x8*)&Ks[0][(row * 4 + (g ^ ((row >> 1) & 3))) * 8] = kv;
        bf16x8 vv = *(const bf16x8*)&vbase[tid * 8];
        *(bf16x8*)&Vs[0][tid * 8] = vv;
    }
    __syncthreads();
    const int qrow = w * 16 + lr;
    const bf16x8 bq = *(const bf16x8*)&Qs[(qrow * 4 + (lg ^ ((qrow >> 1) & 3))) * 8];
    float m = -1e30f, lsum = 0.f;
    f32x4 o[2];
    o[0] = zero; o[1] = zero;

    for (int kc = 0; kc < 8; ++kc) {
        int buf = kc & 1;
        bf16x8 knx, vnx;
        if (kc < 7) {   // issue next-chunk loads early, LDS-write late
            int row = tid >> 2, g = tid & 3;
            knx = *(const bf16x8*)&qkvb[(size_t)(base + (kc + 1) * 64 + row) * 384 + 128 + hd * 32 + g * 8];
            vnx = *(const bf16x8*)&vbase[(size_t)(kc + 1) * 2048 + tid * 8];
        }
        bf16x8 ka[4], va[2][2];
        #pragma unroll
        for (int kf = 0; kf < 4; ++kf) {
            int kr = kf * 16 + lr;
            ka[kf] = *(const bf16x8*)&Ks[buf][(kr * 4 + (lg ^ ((kr >> 1) & 3))) * 8];
        }
        #pragma unroll
        for (int ks = 0; ks < 2; ++ks)
            #pragma unroll
            for (int df = 0; df < 2; ++df) {
                int d = df * 16 + lr;
                int kg = ks * 4 + lg;
                va[ks][df] = *(const bf16x8*)&Vs[buf][(d * 8 + (kg ^ (d & 7))) * 8];
            }
        f32x4 s[4];
        #pragma unroll
        for (int kf = 0; kf < 4; ++kf)
            s[kf] = __builtin_amdgcn_mfma_f32_16x16x32_bf16(ka[kf], bq, zero, 0, 0, 0);
        float v[16];
        #pragma unroll
        for (int kf = 0; kf < 4; ++kf)
            #pragma unroll
            for (int r = 0; r < 4; ++r) v[kf * 4 + r] = s[kf][r] * SCL;
        float rm = fmaxf(fmaxf(fmaxf(fmaxf(v[0], v[1]), fmaxf(v[2], v[3])),
                               fmaxf(fmaxf(v[4], v[5]), fmaxf(v[6], v[7]))),
                         fmaxf(fmaxf(fmaxf(v[8], v[9]), fmaxf(v[10], v[11])),
                               fmaxf(fmaxf(v[12], v[13]), fmaxf(v[14], v[15]))));
        rm = fmaxf(rm, __shfl_xor(rm, 16));
        rm = fmaxf(rm, __shfl_xor(rm, 32));
        float mn = fmaxf(m, rm);
        float alpha = exp2f(m - mn);
        float p[16];
        #pragma unroll
        for (int i = 0; i < 16; ++i) p[i] = exp2f(v[i] - mn);
        float S0 = ((p[0] + p[4]) + p[8]) + p[12];
        float S1 = ((p[1] + p[5]) + p[9]) + p[13];
        float S2 = ((p[2] + p[6]) + p[10]) + p[14];
        float S3 = ((p[3] + p[7]) + p[11]) + p[15];
        float ps = (S0 + S1) + (S2 + S3);
        ps += __shfl_xor(ps, 16);
        ps += __shfl_xor(ps, 32);
        lsum = lsum * alpha + ps;
        m = mn;
        o[0] *= alpha;
        o[1] *= alpha;
        #pragma unroll
        for (int kf = 0; kf < 4; ++kf) {
            uint2 pk;
            pk.x = cvt_pk_bf16(p[kf * 4 + 0], p[kf * 4 + 1]);
            pk.y = cvt_pk_bf16(p[kf * 4 + 2], p[kf * 4 + 3]);
            int gr = (kf * 2 + (lg >> 1)) ^ (lr & 7);
            *(uint2*)&Ps[w][lr * 64 + gr * 8 + (lg & 1) * 4] = pk;
        }
        #pragma unroll
        for (int ks = 0; ks < 2; ++ks) {
            bf16x8 pa = *(const bf16x8*)&Ps[w][lr * 64 + (((ks * 4 + lg) ^ (lr & 7))) * 8];
            #pragma unroll
            for (int df = 0; df < 2; ++df)
                o[df] = __builtin_amdgcn_mfma_f32_16x16x32_bf16(va[ks][df], pa, o[df], 0, 0, 0);
        }
        if (kc < 7) {
            int row = tid >> 2, g = tid & 3;
            *(bf16x8*)&Ks[buf ^ 1][(row * 4 + (g ^ ((row >> 1) & 3))) * 8] = knx;
            *(bf16x8*)&Vs[buf ^ 1][tid * 8] = vnx;
        }
        __syncthreads();
    }
    {
        float inv = 1.f / lsum;
        size_t nrow = (size_t)base + q0 + w * 16 + lr;
        #pragma unroll
        for (int df = 0; df < 2; ++df) {
            uint2 ov;
            ov.x = cvt_pk_bf16(o[df][0] * inv, o[df][1] * inv);
            ov.y = cvt_pk_bf16(o[df][2] * inv, o[df][3] * inv);
            *(uint2*)&ao16[nrow * 128 + hd * 32 + df * 16 + lg * 4] = ov;
        }
    }
}

// ---------------- BN3 finalize + apply: h = sc*t + sh (dual f32 + bf16 write) ----------------
__global__ __launch_bounds__(256) void bn_apply_k(const float* __restrict__ t,
    const float* __restrict__ a3, const float* __restrict__ g3, const float* __restrict__ b3,
    float* __restrict__ h, unsigned short* __restrict__ h16)
{
    __shared__ float sfl[256];
    int tid = threadIdx.x;
    if (tid < 128) {   // identical formula to the old bn_fin_k
        float mean = a3[tid] * (1.f / N_NODES);
        float var  = a3[128 + tid] * (1.f / N_NODES) - mean * mean;
        float sc   = g3[tid] * rsqrtf(var + 1e-5f);
        sfl[tid] = sc;
        sfl[128 + tid] = b3[tid] - mean * sc;
    }
    __syncthreads();
    int idx = blockIdx.x * 256 + tid;
    int cg = (idx & 31) * 4;
    float4 v  = *(const float4*)&t[idx * 4];
    float4 sc = *(const float4*)&sfl[cg];
    float4 sh = *(const float4*)&sfl[128 + cg];
    float4 o;
    o.x = v.x * sc.x + sh.x;
    o.y = v.y * sc.y + sh.y;
    o.z = v.z * sc.z + sh.z;
    o.w = v.w * sc.w + sh.w;
    *(float4*)&h[idx * 4] = o;
    uint2 p;
    p.x = cvt_pk_bf16(o.x, o.y);
    p.y = cvt_pk_bf16(o.z, o.w);
    *(uint2*)&h16[idx * 4] = p;
}

// ---------------- global add pool ----------------
__global__ __launch_bounds__(128) void pool_k(const float* __restrict__ h, float* __restrict__ g)
{
    int b = blockIdx.x, c = threadIdx.x;
    float s = 0.f;
    for (int i = 0; i < NPG; ++i) s += h[(size_t)((b << 9) + i) * C_DIM + c];
    g[b * C_DIM + c] = s;
}

// ---------------- head MLP: [64,128]->64->32->1 ----------------
__global__ __launch_bounds__(256) void head_mlp_k(const float* __restrict__ g,
    const float* __restrict__ w1, const float* __restrict__ b1,
    const float* __restrict__ w2, const float* __restrict__ b2,
    const float* __restrict__ w3, const float* __restrict__ b3,
    float* __restrict__ out)
{
    __shared__ float gs[64 * 128];
    __shared__ float y1[64 * 64];
    __shared__ float y2[64 * 32];
    int tid = threadIdx.x;
    for (int r = 0; r < 32; ++r) gs[r * 256 + tid] = g[r * 256 + tid];
    __syncthreads();
    for (int t = 0; t < 16; ++t) {
        int idx = t * 256 + tid;
        int gi = idx >> 6, c = idx & 63;
        float s = b1[c];
        for (int k = 0; k < 128; ++k) s = fmaf(gs[gi * 128 + k], w1[k * 64 + c], s);
        y1[gi * 64 + c] = fmaxf(s, 0.f);
    }
    __syncthreads();
    for (int t = 0; t < 8; ++t) {
        int idx = t * 256 + tid;
        int gi = idx >> 5, c = idx & 31;
        float s = b2[c];
        for (int k = 0; k < 64; ++k) s = fmaf(y1[gi * 64 + k], w2[k * 32 + c], s);
        y2[gi * 32 + c] = fmaxf(s, 0.f);
    }
    __syncthreads();
    if (tid < 64) {
        float s = b3[0];
        for (int k = 0; k < 32; ++k) s = fmaf(y2[tid * 32 + k], w3[k], s);
        out[tid] = s;
    }
}

extern "C" void kernel_launch(void* const* d_in, const int* in_sizes, int n_in,
                              void* d_out, int out_size, void* d_ws, size_t ws_size,
                              hipStream_t stream)
{
    const int*   x        = (const int*)  d_in[0];
    const float* pe       = (const float*)d_in[1];
    const int*   ei       = (const int*)  d_in[2];
    const int*   eattr    = (const int*)  d_in[3];
    const float* node_emb = (const float*)d_in[5];
    const float* plw      = (const float*)d_in[6];
    const float* plb      = (const float*)d_in[7];
    const float* pe_g     = (const float*)d_in[8];
    const float* pe_b     = (const float*)d_in[9];
    const float* edge_emb = (const float*)d_in[10];
    const float* gw1      = (const float*)d_in[11];
    const float* gb1      = (const float*)d_in[12];
    const float* gw2      = (const float*)d_in[13];
    const float* gb2      = (const float*)d_in[14];
    const float* wqkv     = (const float*)d_in[15];
    const float* bqkv     = (const float*)d_in[16];
    const float* wo       = (const float*)d_in[17];
    const float* bo       = (const float*)d_in[18];
    const float* n1g      = (const float*)d_in[19];
    const float* n1b      = (const float*)d_in[20];
    const float* n2g      = (const float*)d_in[21];
    const float* n2b      = (const float*)d_in[22];
    const float* n3g      = (const float*)d_in[23];
    const float* n3b      = (const float*)d_in[24];
    const float* fw1      = (const float*)d_in[25];
    const float* fb1      = (const float*)d_in[26];
    const float* fw2      = (const float*)d_in[27];
    const float* fb2      = (const float*)d_in[28];
    const float* mw1      = (const float*)d_in[29];
    const float* mb1      = (const float*)d_in[30];
    const float* mw2      = (const float*)d_in[31];
    const float* mb2      = (const float*)d_in[32];
    const float* mw3      = (const float*)d_in[33];
    const float* mb3      = (const float*)d_in[34];

    float* wf  = (float*)d_ws;
    float* Hb  = wf;                                             // h [N,C] f32        [0,1NF)
    unsigned short* Zb16 = (unsigned short*)(wf + (size_t)NF);   // z / attn-out bf16  [1NF,1.5NF)
    float* T1  = wf + 2 * (size_t)NF;                            // t1 / t3 f32        [2NF,3NF)
    unsigned short* QKVb = (unsigned short*)(wf + 3 * (size_t)NF); // qkv bf16 [N,384] [3NF,4.5NF)
    float* T2  = wf + 3 * (size_t)NF;                            // t2 f32 (aliases dead qkv) [3NF,4NF)
    unsigned short* vtg = (unsigned short*)(wf + 4 * (size_t)NF + (size_t)NF / 2); // V^T bf16 [4.5NF,5NF)
    unsigned short* Hb16 = (unsigned short*)(wf + 5 * (size_t)NF); // h bf16 [N,C]     [5NF,5.5NF)
    int* wi     = (int*)(wf + 6 * (size_t)NF);
    int* indptr = wi;                      // N+1
    int* cnt    = wi + 32800;
    int* cnt2   = cnt + N_NODES;
    int* bsum   = cnt2 + N_NODES;          // 128
    int* bpre   = bsum + 128;              // 128
    int* esa    = bpre + 128;              // E packed (src | attr<<16)
    float* st    = (float*)(esa + E_EDGES);
    float* peacc = st;                     // 64
    float* bnacc = st + 64;                // 12*256
    float* gpool = bnacc + 12 * 256;       // 64*128
    short* wT    = (short*)(gpool + 64 * 128);  // 655360 bf16 transposed weights

    const int* srcA = ei;
    const int* dstA = ei + E_EDGES;
    const int LSTR = 163840;

    hipMemsetAsync(peacc, 0, (64 + 12 * 256) * sizeof(float), stream);
    hipMemsetAsync(cnt, 0, 2 * N_NODES * sizeof(int), stream);

    wt_prep_k<<<640, 256, 0, stream>>>(gw1, gw2, wqkv, wo, fw1, fw2, wT);
    pe_stats_k<<<32, 256, 0, stream>>>(pe, peacc);
    h0_k<<<N_NODES / 2, 256, 0, stream>>>(x, pe, node_emb, plw, plb, peacc, pe_g, pe_b, Hb, Hb16);
    hist_k<<<E_EDGES / 256, 256, 0, stream>>>(dstA, cnt);
    bsum_k<<<128, 256, 0, stream>>>(cnt, bsum);
    bscan_k<<<1, 128, 0, stream>>>(bsum, bpre);
    indptr_k<<<128, 256, 0, stream>>>(cnt, bpre, indptr);
    scatter_k<<<E_EDGES / 256, 256, 0, stream>>>(dstA, srcA, eattr, indptr, cnt2, esa);

    for (int l = 0; l < L_LAYERS; ++l) {
        const short* gw1t  = wT + (size_t)l * LSTR;
        const short* gw2t  = wT + (size_t)l * LSTR + 16384;
        const short* wqkvt = wT + (size_t)l * LSTR + 32768;
        const short* wot   = wT + (size_t)l * LSTR + 81920;
        const short* fw1t  = wT + (size_t)l * LSTR + 98304;
        const short* fw2t  = wT + (size_t)l * LSTR + 131072;
        const float* lgb1  = gb1 + (size_t)l * 128;
        const float* lgb2  = gb2 + (size_t)l * 128;
        const float* lbqkv = bqkv + (size_t)l * 384;
        const float* lbo   = bo + (size_t)l * 128;
        const float* lfb1  = fb1 + (size_t)l * 256;
        const float* lfb2  = fb2 + (size_t)l * 128;
        float* acc1 = bnacc + (l * 3 + 0) * 256;
        float* acc2 = bnacc + (l * 3 + 1) * 256;
        float* acc3 = bnacc + (l * 3 + 2) * 256;

        gq_k<<<8960, 256, 0, stream>>>(
            Hb16, esa, indptr, edge_emb, Zb16,
            (const unsigned short*)wqkvt, lbqkv, QKVb, vtg);
        gine_mlp_k<<<256, 512, 0, stream>>>(
            Zb16, (const unsigned short*)gw1t, lgb1, (const unsigned short*)gw2t, lgb2,
            Hb, T1, acc1);
        attn_mfma_k<<<dim3(8, 4, 64), 256, 0, stream>>>(QKVb, vtg, Zb16);
        mgemm_k<128, 128, 0, 1, false, true,  false, true, false><<<dim3(1, 256), 256, 0, stream>>>(
            Zb16, nullptr, nullptr, nullptr, (const unsigned short*)wot, lbo,
            Hb, nullptr, nullptr, nullptr, T2, acc2, nullptr);
        ffn_mlp_k<<<512, 256, 0, stream>>>(
            T1, T2,
            acc1, n1g + l * 128, n1b + l * 128,
            acc2, n2g + l * 128, n2b + l * 128,
            (const unsigned short*)fw1t, lfb1, (const unsigned short*)fw2t, lfb2,
            T1, acc3);
        bn_apply_k<<<NF / 1024, 256, 0, stream>>>(T1, acc3, n3g + l * 128, n3b + l * 128, Hb, Hb16);
    }
    pool_k<<<B_GR, 128, 0, stream>>>(Hb, gpool);
    head_mlp_k<<<1, 256, 0, stream>>>(gpool, mw1, mb1, mw2, mb2, mw3, mb3, (float*)d_out);
}

// Round 16
// 701.168 us; speedup vs baseline: 1.0927x; 1.0927x over previous
//
#include <hip/hip_runtime.h>
#include <math.h>
#include <cstddef>

#define N_NODES 32768
#define C_DIM   128
#define E_EDGES 262144
#define B_GR    64
#define NPG     512
#define WALK_D  20
#define L_LAYERS 4

static constexpr int NF = N_NODES * C_DIM;  // 4,194,304 floats per [N,C] tensor

typedef __attribute__((ext_vector_type(8))) short bf16x8;
typedef __attribute__((ext_vector_type(4))) float f32x4;
typedef __attribute__((ext_vector_type(4))) short short4v;

__device__ inline unsigned short f2bf(float f)
{
    union { float f; unsigned u; } v; v.f = f;
    unsigned r = v.u + 0x7fff + ((v.u >> 16) & 1);
    return (unsigned short)(r >> 16);
}
__device__ inline float bf2f_lo(unsigned u) { return __uint_as_float(u << 16); }
__device__ inline float bf2f_hi(unsigned u) { return __uint_as_float(u & 0xffff0000u); }
// HW packed bf16 convert (RNE, identical bits to f2bf for normal/denormal finite inputs)
__device__ inline unsigned cvt_pk_bf16(float lo, float hi)
{
    unsigned r;
    asm("v_cvt_pk_bf16_f32 %0, %1, %2" : "=v"(r) : "v"(lo), "v"(hi));
    return r;
}

// ---------------- PE batch-norm statistics: register-private + wave reduce ----------------
__global__ __launch_bounds__(256) void pe_stats_k(const float* __restrict__ pe, float* __restrict__ acc)
{
    int gt = blockIdx.x * 256 + threadIdx.x;   // 8192 threads, 4 rows each
    float s[WALK_D], q[WALK_D];
    #pragma unroll
    for (int c = 0; c < WALK_D; ++c) { s[c] = 0.f; q[c] = 0.f; }
    for (int r = 0; r < 4; ++r) {
        const float* row = &pe[(size_t)(gt + r * 8192) * WALK_D];
        float v[20];
        #pragma unroll
        for (int j = 0; j < 5; ++j) *(float4*)&v[j * 4] = *(const float4*)(row + j * 4);
        #pragma unroll
        for (int c = 0; c < WALK_D; ++c) { s[c] += v[c]; q[c] += v[c] * v[c]; }
    }
    #pragma unroll
    for (int c = 0; c < WALK_D; ++c) {
        float ss = s[c], qq = q[c];
        #pragma unroll
        for (int m = 1; m < 64; m <<= 1) { ss += __shfl_xor(ss, m); qq += __shfl_xor(qq, m); }
        if ((threadIdx.x & 63) == 0) { atomicAdd(&acc[c], ss); atomicAdd(&acc[32 + c], qq); }
    }
}

// ---------------- initial embedding h0 = [node_emb[x], BN(pe) @ pe_lin]; pe_fin folded in ----------------
__global__ __launch_bounds__(256) void h0_k(const int* __restrict__ x, const float* __restrict__ pe,
    const float* __restrict__ node_emb, const float* __restrict__ plw, const float* __restrict__ plb,
    const float* __restrict__ peacc, const float* __restrict__ pe_g, const float* __restrict__ pe_b,
    float* __restrict__ h, unsigned short* __restrict__ h16)
{
    __shared__ float spe[64];
    int tid = threadIdx.x;
    if (tid < WALK_D) {
        float mean = peacc[tid] * (1.f / N_NODES);
        float var  = peacc[32 + tid] * (1.f / N_NODES) - mean * mean;
        float sc   = pe_g[tid] * rsqrtf(var + 1e-5f);
        spe[tid] = sc;
        spe[32 + tid] = pe_b[tid] - mean * sc;
    }
    __syncthreads();
    int i = blockIdx.x * 2 + (tid >> 7);
    int c = tid & 127;
    float v;
    if (c < 120) {
        v = node_emb[x[i] * 120 + c];
    } else {
        int pc = c - 120;
        v = plb[pc];
        #pragma unroll
        for (int k = 0; k < WALK_D; ++k) {
            float pn = pe[i * WALK_D + k] * spe[k] + spe[32 + k];
            v = fmaf(pn, plw[k * 8 + pc], v);
        }
    }
    h[i * C_DIM + c] = v;
    h16[i * C_DIM + c] = f2bf(v);
}

// ---------------- CSR build (by destination) ----------------
__global__ __launch_bounds__(256) void hist_k(const int* __restrict__ dst, int* __restrict__ cnt)
{
    int e = blockIdx.x * 256 + threadIdx.x;
    atomicAdd(&cnt[dst[e]], 1);
}

__global__ __launch_bounds__(256) void bsum_k(const int* __restrict__ cnt, int* __restrict__ bsum)
{
    __shared__ int ws[4];
    int b = blockIdx.x, t = threadIdx.x;
    int v = cnt[b * 256 + t];
    #pragma unroll
    for (int m = 1; m < 64; m <<= 1) v += __shfl_xor(v, m);
    if ((t & 63) == 0) ws[t >> 6] = v;
    __syncthreads();
    if (t == 0) bsum[b] = ws[0] + ws[1] + ws[2] + ws[3];
}

__global__ __launch_bounds__(128) void bscan_k(const int* __restrict__ bsum, int* __restrict__ bpre)
{
    __shared__ int s[128];
    int t = threadIdx.x;
    int v = bsum[t];
    s[t] = v;
    __syncthreads();
    for (int off = 1; off < 128; off <<= 1) {
        int u = (t >= off) ? s[t - off] : 0;
        __syncthreads();
        s[t] += u;
        __syncthreads();
    }
    bpre[t] = s[t] - v;
}

__global__ __launch_bounds__(256) void indptr_k(const int* __restrict__ cnt, const int* __restrict__ bpre,
                                                int* __restrict__ indptr)
{
    __shared__ int s[256];
    int b = blockIdx.x, t = threadIdx.x;
    int v = cnt[b * 256 + t];
    s[t] = v;
    __syncthreads();
    for (int off = 1; off < 256; off <<= 1) {
        int u = (t >= off) ? s[t - off] : 0;
        __syncthreads();
        s[t] += u;
        __syncthreads();
    }
    indptr[b * 256 + t] = bpre[b] + s[t] - v;
    if (b == 127 && t == 255) indptr[N_NODES] = E_EDGES;
}

// ---------------- scatter + edge-record build: esa[pos] = src | attr<<16 ----------------
__global__ __launch_bounds__(256) void scatter_k(const int* __restrict__ dst, const int* __restrict__ src,
                                                 const int* __restrict__ attr, const int* __restrict__ indptr,
                                                 int* __restrict__ cur, int* __restrict__ esa)
{
    int e = blockIdx.x * 256 + threadIdx.x;
    int d = dst[e];
    int pos = atomicAdd(&cur[d], 1);
    esa[indptr[d] + pos] = src[e] | (attr[e] << 16);
}

// ---------------- GINE message aggregation (bf16 in/out): z = h + sum_in relu(h[src]+ee) ----------------
__global__ __launch_bounds__(256) void gine_gather_k(const unsigned short* __restrict__ h16,
    const int* __restrict__ esa, const int* __restrict__ indptr,
    const float* __restrict__ edge_emb, unsigned short* __restrict__ z16)
{
    __shared__ float ee[4 * C_DIM];
    int tid = threadIdx.x;
    ee[tid] = edge_emb[tid];
    ee[tid + 256] = edge_emb[tid + 256];
    __syncthreads();
    int i = blockIdx.x * 4 + (tid >> 6);
    int c = (tid & 63) * 2;
    int p0 = indptr[i], p1 = indptr[i + 1];
    float s0 = 0.f, s1 = 0.f;
    int p = p0;
    for (; p + 4 <= p1; p += 4) {
        int sa0 = esa[p], sa1 = esa[p + 1], sa2 = esa[p + 2], sa3 = esa[p + 3];
        unsigned u0 = *(const unsigned*)&h16[(size_t)(sa0 & 0xffff) * C_DIM + c];
        unsigned u1 = *(const unsigned*)&h16[(size_t)(sa1 & 0xffff) * C_DIM + c];
        unsigned u2 = *(const unsigned*)&h16[(size_t)(sa2 & 0xffff) * C_DIM + c];
        unsigned u3 = *(const unsigned*)&h16[(size_t)(sa3 & 0xffff) * C_DIM + c];
        float2 e0 = *(const float2*)&ee[(sa0 >> 16) * C_DIM + c];
        float2 e1 = *(const float2*)&ee[(sa1 >> 16) * C_DIM + c];
        float2 e2 = *(const float2*)&ee[(sa2 >> 16) * C_DIM + c];
        float2 e3 = *(const float2*)&ee[(sa3 >> 16) * C_DIM + c];
        s0 += fmaxf(bf2f_lo(u0) + e0.x, 0.f); s1 += fmaxf(bf2f_hi(u0) + e0.y, 0.f);
        s0 += fmaxf(bf2f_lo(u1) + e1.x, 0.f); s1 += fmaxf(bf2f_hi(u1) + e1.y, 0.f);
        s0 += fmaxf(bf2f_lo(u2) + e2.x, 0.f); s1 += fmaxf(bf2f_hi(u2) + e2.y, 0.f);
        s0 += fmaxf(bf2f_lo(u3) + e3.x, 0.f); s1 += fmaxf(bf2f_hi(u3) + e3.y, 0.f);
    }
    for (; p < p1; ++p) {
        int sa = esa[p];
        unsigned u = *(const unsigned*)&h16[(size_t)(sa & 0xffff) * C_DIM + c];
        float2 ev = *(const float2*)&ee[(sa >> 16) * C_DIM + c];
        s0 += fmaxf(bf2f_lo(u) + ev.x, 0.f);
        s1 += fmaxf(bf2f_hi(u) + ev.y, 0.f);
    }
    unsigned us = *(const unsigned*)&h16[(size_t)i * C_DIM + c];
    s0 += bf2f_lo(us);
    s1 += bf2f_hi(us);
    *(unsigned*)&z16[(size_t)i * C_DIM + c] = cvt_pk_bf16(s0, s1);
}

// ---------------- weight prep: W[K][N] f32 -> Wt[N][K] bf16, all 24 matrices ----------------
__global__ __launch_bounds__(256) void wt_prep_k(
    const float* __restrict__ gw1, const float* __restrict__ gw2,
    const float* __restrict__ wqkv, const float* __restrict__ wo,
    const float* __restrict__ fw1, const float* __restrict__ fw2,
    short* __restrict__ out)
{
    __shared__ float ts[32][36];
    int b = blockIdx.x;
    int l = b / 160, t = b % 160;
    const float* src; int K, N; size_t obase; int tile;
    if (t < 16)       { src = gw1  + (size_t)l * 16384; K = 128; N = 128; obase = (size_t)l * 163840 + 0;      tile = t; }
    else if (t < 32)  { src = gw2  + (size_t)l * 16384; K = 128; N = 128; obase = (size_t)l * 163840 + 16384;  tile = t - 16; }
    else if (t < 80)  { src = wqkv + (size_t)l * 49152; K = 128; N = 384; obase = (size_t)l * 163840 + 32768;  tile = t - 32; }
    else if (t < 96)  { src = wo   + (size_t)l * 16384; K = 128; N = 128; obase = (size_t)l * 163840 + 81920;  tile = t - 80; }
    else if (t < 128) { src = fw1  + (size_t)l * 32768; K = 128; N = 256; obase = (size_t)l * 163840 + 98304;  tile = t - 96; }
    else              { src = fw2  + (size_t)l * 32768; K = 256; N = 128; obase = (size_t)l * 163840 + 131072; tile = t - 128; }
    int ntN = N / 32;
    int tk = tile / ntN, tn = tile % ntN;
    int tid = threadIdx.x;
    int r = tid >> 3, c4 = (tid & 7) * 4;
    *(float4*)&ts[r][c4] = *(const float4*)&src[(size_t)(tk * 32 + r) * N + tn * 32 + c4];
    __syncthreads();
    int n = tid >> 3, k4 = (tid & 7) * 4;
    short4v pk;
    #pragma unroll
    for (int i2 = 0; i2 < 4; ++i2) pk[i2] = (short)f2bf(ts[k4 + i2][n]);
    *(short4v*)&out[obase + (size_t)(tn * 32 + n) * K + tk * 32 + k4] = pk;
}

// ---------------- MFMA bf16 GEMM (B staged in 64-col halves; 48KB LDS -> 3 blocks/CU) ----------------
// VOUT: for the qkv GEMM, col-block at col0==256 (the V part) writes the pre-swizzled
// vtg image directly instead of Cout. Per-output MFMA order identical to the full-B version.
template<int KD, int NC, int AMODE, int RESMODE, bool RELU, bool STATS, bool OUTBF, bool ABF, bool VOUT>
__global__ __launch_bounds__(256) void mgemm_k(
    const void* __restrict__ Av, const float* __restrict__ A2,
    const float* __restrict__ affA1, const float* __restrict__ affA2,
    const unsigned short* __restrict__ Bt, const float* __restrict__ bias,
    const float* __restrict__ R1, const float* __restrict__ R2,
    const float* __restrict__ affR1, const float* __restrict__ affR2,
    void* __restrict__ Cout, float* __restrict__ stats,
    unsigned short* __restrict__ vtg)
{
    __shared__ short As[16384];   // [128 rows][128 k] bf16, XOR-swizzled granules
    __shared__ short Bs[8192];    // [64 cols][128 k] bf16 (current half)
    const int tid = threadIdx.x;
    const int w = tid >> 6;
    const int lane = tid & 63;
    const int lr = lane & 15, lg = lane >> 4;
    const int row0 = blockIdx.y * 128;
    const int col0 = blockIdx.x * 128;

    const f32x4 zero = {0.f, 0.f, 0.f, 0.f};
    f32x4 acc[2][8];
    #pragma unroll
    for (int i = 0; i < 2; ++i)
        #pragma unroll
        for (int cf = 0; cf < 8; ++cf) acc[i][cf] = zero;

    for (int kt = 0; kt < KD / 128; ++kt) {
        if (kt > 0) __syncthreads();
        #pragma unroll
        for (int it = 0; it < 8; ++it) {
            int gid = it * 256 + tid;
            int row = gid >> 4, g = gid & 15;
            bf16x8 pk;
            if (ABF) {
                pk = *(const bf16x8*)&((const unsigned short*)Av)[(size_t)(row0 + row) * KD + kt * 128 + g * 8];
            } else {
                const float* Af = (const float*)Av;
                const float* ap = &Af[(size_t)(row0 + row) * KD + kt * 128 + g * 8];
                float v[8];
                *(float4*)&v[0] = *(const float4*)ap;
                *(float4*)&v[4] = *(const float4*)(ap + 4);
                if (AMODE == 1) {
                    const float* ap2 = &A2[(size_t)(row0 + row) * KD + kt * 128 + g * 8];
                    float u[8];
                    *(float4*)&u[0] = *(const float4*)ap2;
                    *(float4*)&u[4] = *(const float4*)(ap2 + 4);
                    #pragma unroll
                    for (int j = 0; j < 8; ++j) {
                        int ck = g * 8 + j;
                        v[j] = v[j] * affA1[ck] + affA1[128 + ck] + u[j] * affA2[ck] + affA2[128 + ck];
                    }
                }
                #pragma unroll
                for (int j = 0; j < 8; ++j) pk[j] = (short)f2bf(v[j]);
            }
            *(bf16x8*)&As[(row * 16 + (g ^ (row & 7))) * 8] = pk;
        }
        #pragma unroll
        for (int h = 0; h < 2; ++h) {
            if (h > 0) __syncthreads();   // prior Bs reads done
            #pragma unroll
            for (int it = 0; it < 4; ++it) {
                int gid = it * 256 + tid;
                int row = gid >> 4, g = gid & 15;   // row = local B col in half
                bf16x8 bv = *(const bf16x8*)&Bt[(size_t)(col0 + h * 64 + row) * KD + kt * 128 + g * 8];
                *(bf16x8*)&Bs[(row * 16 + (g ^ (row & 7))) * 8] = bv;
            }
            __syncthreads();
            #pragma unroll
            for (int ks = 0; ks < 4; ++ks) {
                bf16x8 af[2], bfr[4];
                #pragma unroll
                for (int i = 0; i < 2; ++i) {
                    int row = w * 32 + i * 16 + lr;
                    int g = ks * 4 + lg;
                    af[i] = *(const bf16x8*)&As[(row * 16 + (g ^ (row & 7))) * 8];
                }
                #pragma unroll
                for (int cfl = 0; cfl < 4; ++cfl) {
                    int lc = cfl * 16 + lr;   // local col in half; (col&7)==(lc&7)
                    int g = ks * 4 + lg;
                    bfr[cfl] = *(const bf16x8*)&Bs[(lc * 16 + (g ^ (lc & 7))) * 8];
                }
                #pragma unroll
                for (int i = 0; i < 2; ++i)
                    #pragma unroll
                    for (int cfl = 0; cfl < 4; ++cfl)
                        acc[i][h * 4 + cfl] = __builtin_amdgcn_mfma_f32_16x16x32_bf16(af[i], bfr[cfl], acc[i][h * 4 + cfl], 0, 0, 0);
            }
        }
    }

    float* cs = (float*)As;       // alias LDS after compute
    float* cq = cs + 128;
    if (STATS) {
        __syncthreads();
        if (tid < 128) { cs[tid] = 0.f; cq[tid] = 0.f; }
        __syncthreads();
    }
    float bs_v[8];
    #pragma unroll
    for (int cf = 0; cf < 8; ++cf) bs_v[cf] = bias[col0 + cf * 16 + lr];
    float rs1[8], ro1[8], rs2[8], ro2[8];
    if (RESMODE == 2) {
        #pragma unroll
        for (int cf = 0; cf < 8; ++cf) {
            int c = cf * 16 + lr;
            rs1[cf] = affR1[c]; ro1[cf] = affR1[128 + c];
            rs2[cf] = affR2[c]; ro2[cf] = affR2[128 + c];
        }
    }
    float colS[8], colQ[8];
    #pragma unroll
    for (int cf = 0; cf < 8; ++cf) { colS[cf] = 0.f; colQ[cf] = 0.f; }
    const bool vblk = VOUT && (col0 == 256);
    #pragma unroll
    for (int i = 0; i < 2; ++i) {
        #pragma unroll
        for (int r = 0; r < 4; ++r) {
            size_t grow = row0 + w * 32 + i * 16 + lg * 4 + r;
            #pragma unroll
            for (int cf = 0; cf < 8; ++cf) {
                int c = col0 + cf * 16 + lr;
                float val = acc[i][cf][r] + bs_v[cf];
                if (RESMODE == 1) val += R1[grow * NC + c];
                if (RESMODE == 2) {
                    val += R1[grow * 128 + c] * rs1[cf] + ro1[cf]
                         + R2[grow * 128 + c] * rs2[cf] + ro2[cf];
                }
                if (RELU) val = fmaxf(val, 0.f);
                if (VOUT && vblk) {
                    int g2 = (int)(grow >> 9);
                    int key = (int)(grow & 511);
                    int kc = key >> 6, kg = (key >> 3) & 7, j = key & 7;
                    int cd = c - 256;
                    int hd2 = cd >> 5, dd = cd & 31;
                    vtg[((size_t)(g2 * 4 + hd2) * 8 + kc) * 2048 + dd * 64 + ((kg ^ (dd & 7)) << 3) + j] = f2bf(val);
                } else if (OUTBF) {
                    ((unsigned short*)Cout)[grow * NC + c] = f2bf(val);
                } else {
                    ((float*)Cout)[grow * NC + c] = val;
                }
                if (STATS) { colS[cf] += val; colQ[cf] += val * val; }
            }
        }
    }
    if (STATS) {
        #pragma unroll
        for (int cf = 0; cf < 8; ++cf) {
            float s = colS[cf], q = colQ[cf];
            s += __shfl_xor(s, 16); s += __shfl_xor(s, 32);
            q += __shfl_xor(q, 16); q += __shfl_xor(q, 32);
            if (lg == 0) { atomicAdd(&cs[cf * 16 + lr], s); atomicAdd(&cq[cf * 16 + lr], q); }
        }
        __syncthreads();
        if (tid < 128) {
            atomicAdd(&stats[tid], cs[tid]);
            atomicAdd(&stats[128 + tid], cq[tid]);
        }
    }
}

// ---------------- fused GINE MLP, 512 threads / 8 waves, 128-row tile ----------------
__global__ __launch_bounds__(512) void gine_mlp_k(
    const unsigned short* __restrict__ z16,
    const unsigned short* __restrict__ W1t, const float* __restrict__ b1,
    const unsigned short* __restrict__ W2t, const float* __restrict__ b2,
    const float* __restrict__ Hres,
    float* __restrict__ T1out, float* __restrict__ stats)
{
    __shared__ short As[16384];
    __shared__ short Bs[16384];
    const int tid = threadIdx.x;
    const int w = tid >> 6;          // 0..7
    const int lane = tid & 63;
    const int lr = lane & 15, lg = lane >> 4;
    const int row0 = blockIdx.x * 128;
    const f32x4 zero = {0.f, 0.f, 0.f, 0.f};
    const int arow = w * 16 + lr;

    #pragma unroll
    for (int it = 0; it < 4; ++it) {
        int gid = it * 512 + tid;
        int row = gid >> 4, g = gid & 15;
        bf16x8 av = *(const bf16x8*)&z16[(size_t)(row0 + row) * 128 + g * 8];
        *(bf16x8*)&As[(row * 16 + (g ^ (row & 7))) * 8] = av;
        bf16x8 bv = *(const bf16x8*)&W1t[(size_t)row * 128 + g * 8];
        *(bf16x8*)&Bs[(row * 16 + (g ^ (row & 7))) * 8] = bv;
    }
    __syncthreads();

    f32x4 acc[8];
    #pragma unroll
    for (int cf = 0; cf < 8; ++cf) acc[cf] = zero;
    #pragma unroll
    for (int ks = 0; ks < 4; ++ks) {
        int g = ks * 4 + lg;
        bf16x8 af = *(const bf16x8*)&As[(arow * 16 + (g ^ (arow & 7))) * 8];
        #pragma unroll
        for (int cf = 0; cf < 8; ++cf) {
            int c = cf * 16 + lr;
            bf16x8 bfr = *(const bf16x8*)&Bs[(c * 16 + (g ^ (c & 7))) * 8];
            acc[cf] = __builtin_amdgcn_mfma_f32_16x16x32_bf16(af, bfr, acc[cf], 0, 0, 0);
        }
    }
    __syncthreads();   // all As(z)/Bs(W1) reads complete

    {   // Y = f2bf(relu(acc + b1)) -> As (same swizzled positions & rounding point)
        float bias1[8];
        #pragma unroll
        for (int cf = 0; cf < 8; ++cf) bias1[cf] = b1[cf * 16 + lr];
        #pragma unroll
        for (int r = 0; r < 4; ++r) {
            int row = w * 16 + lg * 4 + r;
            #pragma unroll
            for (int cf = 0; cf < 8; ++cf) {
                int col = cf * 16 + lr;
                float val = fmaxf(acc[cf][r] + bias1[cf], 0.f);
                As[(row * 16 + ((col >> 3) ^ (row & 7))) * 8 + (col & 7)] = (short)f2bf(val);
            }
        }
    }
    #pragma unroll
    for (int it = 0; it < 4; ++it) {
        int gid = it * 512 + tid;
        int row = gid >> 4, g = gid & 15;
        bf16x8 bv = *(const bf16x8*)&W2t[(size_t)row * 128 + g * 8];
        *(bf16x8*)&Bs[(row * 16 + (g ^ (row & 7))) * 8] = bv;
    }
    __syncthreads();

    #pragma unroll
    for (int cf = 0; cf < 8; ++cf) acc[cf] = zero;
    #pragma unroll
    for (int ks = 0; ks < 4; ++ks) {
        int g = ks * 4 + lg;
        bf16x8 af = *(const bf16x8*)&As[(arow * 16 + (g ^ (arow & 7))) * 8];
        #pragma unroll
        for (int cf = 0; cf < 8; ++cf) {
            int c = cf * 16 + lr;
            bf16x8 bfr = *(const bf16x8*)&Bs[(c * 16 + (g ^ (c & 7))) * 8];
            acc[cf] = __builtin_amdgcn_mfma_f32_16x16x32_bf16(af, bfr, acc[cf], 0, 0, 0);
        }
    }

    float* cs = (float*)As;
    float* cq = cs + 128;
    __syncthreads();
    if (tid < 128) { cs[tid] = 0.f; cq[tid] = 0.f; }
    __syncthreads();
    float bs_v[8];
    #pragma unroll
    for (int cf = 0; cf < 8; ++cf) bs_v[cf] = b2[cf * 16 + lr];
    float colS[8], colQ[8];
    #pragma unroll
    for (int cf = 0; cf < 8; ++cf) { colS[cf] = 0.f; colQ[cf] = 0.f; }
    #pragma unroll
    for (int r = 0; r < 4; ++r) {
        size_t grow = row0 + w * 16 + lg * 4 + r;
        #pragma unroll
        for (int cf = 0; cf < 8; ++cf) {
            int c = cf * 16 + lr;
            float val = acc[cf][r] + bs_v[cf] + Hres[grow * 128 + c];
            T1out[grow * 128 + c] = val;
            colS[cf] += val; colQ[cf] += val * val;
        }
    }
    #pragma unroll
    for (int cf = 0; cf < 8; ++cf) {
        float s = colS[cf], q = colQ[cf];
        s += __shfl_xor(s, 16); s += __shfl_xor(s, 32);
        q += __shfl_xor(q, 16); q += __shfl_xor(q, 32);
        if (lg == 0) { atomicAdd(&cs[cf * 16 + lr], s); atomicAdd(&cq[cf * 16 + lr], q); }
    }
    __syncthreads();
    if (tid < 128) {
        atomicAdd(&stats[tid], cs[tid]);
        atomicAdd(&stats[128 + tid], cq[tid]);
    }
}

// ---------------- fused FFN (+ BN1/BN2 finalize in prologue): T1 = FFN(...) + aff(T1,T2), BN3 stats ----
__global__ __launch_bounds__(256) void ffn_mlp_k(
    const float* __restrict__ T1, const float* __restrict__ T2,
    const float* __restrict__ a1, const float* __restrict__ g1v, const float* __restrict__ b1v,
    const float* __restrict__ a2, const float* __restrict__ g2v, const float* __restrict__ b2v,
    const unsigned short* __restrict__ W1t, const float* __restrict__ fb1,
    const unsigned short* __restrict__ W2t, const float* __restrict__ fb2,
    float* __restrict__ T1out, float* __restrict__ stats)
{
    __shared__ short As[8192];    // [64 rows][128 k]
    __shared__ short Bs[16384];   // [128][128] (W1 col-half / W2 k-half)
    __shared__ short Ys[8192];    // [64 rows][128 hidden] current half
    __shared__ float sf1l[256], sf2l[256];
    const int tid = threadIdx.x;
    const int w = tid >> 6;
    const int lane = tid & 63;
    const int lr = lane & 15, lg = lane >> 4;
    const int row0 = blockIdx.x * 64;
    const f32x4 zero = {0.f, 0.f, 0.f, 0.f};

    if (tid < 128) {   // BN1/BN2 finalize (identical formula to the old bn_fin_k)
        float mean = a1[tid] * (1.f / N_NODES);
        float var  = a1[128 + tid] * (1.f / N_NODES) - mean * mean;
        float sc   = g1v[tid] * rsqrtf(var + 1e-5f);
        sf1l[tid] = sc; sf1l[128 + tid] = b1v[tid] - mean * sc;
        mean = a2[tid] * (1.f / N_NODES);
        var  = a2[128 + tid] * (1.f / N_NODES) - mean * mean;
        sc   = g2v[tid] * rsqrtf(var + 1e-5f);
        sf2l[tid] = sc; sf2l[128 + tid] = b2v[tid] - mean * sc;
    }
    __syncthreads();

    #pragma unroll
    for (int it = 0; it < 4; ++it) {
        int gid = it * 256 + tid;
        int row = gid >> 4, g = gid & 15;
        const float* ap = &T1[(size_t)(row0 + row) * 128 + g * 8];
        const float* ap2 = &T2[(size_t)(row0 + row) * 128 + g * 8];
        float v[8], u[8];
        *(float4*)&v[0] = *(const float4*)ap;
        *(float4*)&v[4] = *(const float4*)(ap + 4);
        *(float4*)&u[0] = *(const float4*)ap2;
        *(float4*)&u[4] = *(const float4*)(ap2 + 4);
        unsigned pw[4];
        #pragma unroll
        for (int j2 = 0; j2 < 4; ++j2) {
            int ck0 = g * 8 + j2 * 2, ck1 = ck0 + 1;
            float x0 = v[j2 * 2]     * sf1l[ck0] + sf1l[128 + ck0] + u[j2 * 2]     * sf2l[ck0] + sf2l[128 + ck0];
            float x1 = v[j2 * 2 + 1] * sf1l[ck1] + sf1l[128 + ck1] + u[j2 * 2 + 1] * sf2l[ck1] + sf2l[128 + ck1];
            pw[j2] = cvt_pk_bf16(x0, x1);
        }
        *(uint4*)&As[(row * 16 + (g ^ (row & 7))) * 8] = *(uint4*)pw;
    }

    f32x4 acc2[8];
    #pragma unroll
    for (int cf = 0; cf < 8; ++cf) acc2[cf] = zero;

    const int arow = w * 16 + lr;
    for (int h = 0; h < 2; ++h) {
        if (h > 0) __syncthreads();
        #pragma unroll
        for (int it = 0; it < 8; ++it) {
            int gid = it * 256 + tid;
            int row = gid >> 4, g = gid & 15;
            bf16x8 bv = *(const bf16x8*)&W1t[(size_t)(h * 128 + row) * 128 + g * 8];
            *(bf16x8*)&Bs[(row * 16 + (g ^ (row & 7))) * 8] = bv;
        }
        __syncthreads();
        f32x4 accY[8];
        #pragma unroll
        for (int cf = 0; cf < 8; ++cf) accY[cf] = zero;
        #pragma unroll
        for (int ks = 0; ks < 4; ++ks) {
            int g = ks * 4 + lg;
            bf16x8 af = *(const bf16x8*)&As[(arow * 16 + (g ^ (arow & 7))) * 8];
            #pragma unroll
            for (int cf = 0; cf < 8; ++cf) {
                int c = cf * 16 + lr;
                bf16x8 bfr = *(const bf16x8*)&Bs[(c * 16 + (g ^ (c & 7))) * 8];
                accY[cf] = __builtin_amdgcn_mfma_f32_16x16x32_bf16(af, bfr, accY[cf], 0, 0, 0);
            }
        }
        __syncthreads();
        #pragma unroll
        for (int r = 0; r < 4; ++r) {
            int row = w * 16 + lg * 4 + r;
            #pragma unroll
            for (int cf = 0; cf < 8; ++cf) {
                int col = cf * 16 + lr;
                float val = fmaxf(accY[cf][r] + fb1[h * 128 + col], 0.f);
                Ys[(row * 16 + ((col >> 3) ^ (row & 7))) * 8 + (col & 7)] = (short)f2bf(val);
            }
        }
        #pragma unroll
        for (int it = 0; it < 8; ++it) {
            int gid = it * 256 + tid;
            int row = gid >> 4, g = gid & 15;
            bf16x8 bv = *(const bf16x8*)&W2t[(size_t)row * 256 + h * 128 + g * 8];
            *(bf16x8*)&Bs[(row * 16 + (g ^ (row & 7))) * 8] = bv;
        }
        __syncthreads();
        #pragma unroll
        for (int ks = 0; ks < 4; ++ks) {
            int g = ks * 4 + lg;
            bf16x8 af = *(const bf16x8*)&Ys[(arow * 16 + (g ^ (arow & 7))) * 8];
            #pragma unroll
            for (int cf = 0; cf < 8; ++cf) {
                int c = cf * 16 + lr;
                bf16x8 bfr = *(const bf16x8*)&Bs[(c * 16 + (g ^ (c & 7))) * 8];
                acc2[cf] = __builtin_amdgcn_mfma_f32_16x16x32_bf16(af, bfr, acc2[cf], 0, 0, 0);
            }
        }
    }

    float* cs = (float*)As;
    float* cq = cs + 128;
    __syncthreads();
    if (tid < 128) { cs[tid] = 0.f; cq[tid] = 0.f; }
    __syncthreads();
    float bs_v[8], rs1[8], ro1[8], rs2[8], ro2[8];
    #pragma unroll
    for (int cf = 0; cf < 8; ++cf) {
        int c = cf * 16 + lr;
        bs_v[cf] = fb2[c];
        rs1[cf] = sf1l[c]; ro1[cf] = sf1l[128 + c];
        rs2[cf] = sf2l[c]; ro2[cf] = sf2l[128 + c];
    }
    float colS[8], colQ[8];
    #pragma unroll
    for (int cf = 0; cf < 8; ++cf) { colS[cf] = 0.f; colQ[cf] = 0.f; }
    #pragma unroll
    for (int r = 0; r < 4; ++r) {
        size_t grow = row0 + w * 16 + lg * 4 + r;
        #pragma unroll
        for (int cf = 0; cf < 8; ++cf) {
            int c = cf * 16 + lr;
            float val = acc2[cf][r] + bs_v[cf]
                      + T1[grow * 128 + c] * rs1[cf] + ro1[cf]
                      + T2[grow * 128 + c] * rs2[cf] + ro2[cf];
            T1out[grow * 128 + c] = val;
            colS[cf] += val; colQ[cf] += val * val;
        }
    }
    #pragma unroll
    for (int cf = 0; cf < 8; ++cf) {
        float s = colS[cf], q = colQ[cf];
        s += __shfl_xor(s, 16); s += __shfl_xor(s, 32);
        q += __shfl_xor(q, 16); q += __shfl_xor(q, 32);
        if (lg == 0) { atomicAdd(&cs[cf * 16 + lr], s); atomicAdd(&cq[cf * 16 + lr], q); }
    }
    __syncthreads();
    if (tid < 128) {
        atomicAdd(&stats[tid], cs[tid]);
        atomicAdd(&stats[128 + tid], cq[tid]);
    }
}

// ---------------- MFMA flash attention, swapped-QK core, 64 q/block (bitwise-identical) ----------------
__global__ __launch_bounds__(256) void attn_mfma_k(const unsigned short* __restrict__ qkvb,
                                                   const unsigned short* __restrict__ vtg,
                                                   unsigned short* __restrict__ ao16)
{
    __shared__ short Qs[2048];      // [64 q][4 dg ^swz][8]
    __shared__ short Ks[2][2048];   // [64 k][4 dg ^swz][8], double-buffered
    __shared__ short Vs[2][2048];   // pre-swizzled V^T image, double-buffered
    __shared__ short Ps[4][1024];   // per-wave P^T [16 q][8 kgran ^swz][8]
    const int tid = threadIdx.x;
    const int w = tid >> 6, lane = tid & 63;
    const int lr = lane & 15, lg = lane >> 4;
    const int q0 = blockIdx.x * 64;
    const int hd = blockIdx.y;
    const int base = blockIdx.z * NPG;
    const float SCL = 0.17677669529663687f * 1.44269504089f;  // 1/sqrt(32) * log2(e)
    const f32x4 zero = {0.f, 0.f, 0.f, 0.f};
    const unsigned short* vbase = vtg + (size_t)(blockIdx.z * 4 + hd) * 16384;

    {   // stage Q (64 rows) + chunk 0 of K/V
        int row = tid >> 2, g = tid & 3;
        bf16x8 qv = *(const bf16x8*)&qkvb[(size_t)(base + q0 + row) * 384 + hd * 32 + g * 8];
        *(bf16x8*)&Qs[(row * 4 + (g ^ ((row >> 1) & 3))) * 8] = qv;
        bf16x8 kv = *(const bf16x8*)&qkvb[(size_t)(base + row) * 384 + 128 + hd * 32 + g * 8];
        *(bf16x8*)&Ks[0][(row * 4 + (g ^ ((row >> 1) & 3))) * 8] = kv;
        bf16x8 vv = *(const bf16x8*)&vbase[tid * 8];
        *(bf16x8*)&Vs[0][tid * 8] = vv;
    }
    __syncthreads();
    const int qrow = w * 16 + lr;
    const bf16x8 bq = *(const bf16x8*)&Qs[(qrow * 4 + (lg ^ ((qrow >> 1) & 3))) * 8];
    float m = -1e30f, lsum = 0.f;
    f32x4 o[2];
    o[0] = zero; o[1] = zero;

    for (int kc = 0; kc < 8; ++kc) {
        int buf = kc & 1;
        bf16x8 knx, vnx;
        if (kc < 7) {   // issue next-chunk loads early, LDS-write late
            int row = tid >> 2, g = tid & 3;
            knx = *(const bf16x8*)&qkvb[(size_t)(base + (kc + 1) * 64 + row) * 384 + 128 + hd * 32 + g * 8];
            vnx = *(const bf16x8*)&vbase[(size_t)(kc + 1) * 2048 + tid * 8];
        }
        bf16x8 ka[4], va[2][2];
        #pragma unroll
        for (int kf = 0; kf < 4; ++kf) {
            int kr = kf * 16 + lr;
            ka[kf] = *(const bf16x8*)&Ks[buf][(kr * 4 + (lg ^ ((kr >> 1) & 3))) * 8];
        }
        #pragma unroll
        for (int ks = 0; ks < 2; ++ks)
            #pragma unroll
            for (int df = 0; df < 2; ++df) {
                int d = df * 16 + lr;
                int kg = ks * 4 + lg;
                va[ks][df] = *(const bf16x8*)&Vs[buf][(d * 8 + (kg ^ (d & 7))) * 8];
            }
        f32x4 s[4];
        #pragma unroll
        for (int kf = 0; kf < 4; ++kf)
            s[kf] = __builtin_amdgcn_mfma_f32_16x16x32_bf16(ka[kf], bq, zero, 0, 0, 0);
        float v[16];
        #pragma unroll
        for (int kf = 0; kf < 4; ++kf)
            #pragma unroll
            for (int r = 0; r < 4; ++r) v[kf * 4 + r] = s[kf][r] * SCL;
        float rm = fmaxf(fmaxf(fmaxf(fmaxf(v[0], v[1]), fmaxf(v[2], v[3])),
                               fmaxf(fmaxf(v[4], v[5]), fmaxf(v[6], v[7]))),
                         fmaxf(fmaxf(fmaxf(v[8], v[9]), fmaxf(v[10], v[11])),
                               fmaxf(fmaxf(v[12], v[13]), fmaxf(v[14], v[15]))));
        rm = fmaxf(rm, __shfl_xor(rm, 16));
        rm = fmaxf(rm, __shfl_xor(rm, 32));
        float mn = fmaxf(m, rm);
        float alpha = exp2f(m - mn);
        float p[16];
        #pragma unroll
        for (int i = 0; i < 16; ++i) p[i] = exp2f(v[i] - mn);
        float S0 = ((p[0] + p[4]) + p[8]) + p[12];
        float S1 = ((p[1] + p[5]) + p[9]) + p[13];
        float S2 = ((p[2] + p[6]) + p[10]) + p[14];
        float S3 = ((p[3] + p[7]) + p[11]) + p[15];
        float ps = (S0 + S1) + (S2 + S3);
        ps += __shfl_xor(ps, 16);
        ps += __shfl_xor(ps, 32);
        lsum = lsum * alpha + ps;
        m = mn;
        o[0] *= alpha;
        o[1] *= alpha;
        #pragma unroll
        for (int kf = 0; kf < 4; ++kf) {
            uint2 pk;
            pk.x = cvt_pk_bf16(p[kf * 4 + 0], p[kf * 4 + 1]);
            pk.y = cvt_pk_bf16(p[kf * 4 + 2], p[kf * 4 + 3]);
            int gr = (kf * 2 + (lg >> 1)) ^ (lr & 7);
            *(uint2*)&Ps[w][lr * 64 + gr * 8 + (lg & 1) * 4] = pk;
        }
        #pragma unroll
        for (int ks = 0; ks < 2; ++ks) {
            bf16x8 pa = *(const bf16x8*)&Ps[w][lr * 64 + (((ks * 4 + lg) ^ (lr & 7))) * 8];
            #pragma unroll
            for (int df = 0; df < 2; ++df)
                o[df] = __builtin_amdgcn_mfma_f32_16x16x32_bf16(va[ks][df], pa, o[df], 0, 0, 0);
        }
        if (kc < 7) {
            int row = tid >> 2, g = tid & 3;
            *(bf16x8*)&Ks[buf ^ 1][(row * 4 + (g ^ ((row >> 1) & 3))) * 8] = knx;
            *(bf16x8*)&Vs[buf ^ 1][tid * 8] = vnx;
        }
        __syncthreads();
    }
    {
        float inv = 1.f / lsum;
        size_t nrow = (size_t)base + q0 + w * 16 + lr;
        #pragma unroll
        for (int df = 0; df < 2; ++df) {
            uint2 ov;
            ov.x = cvt_pk_bf16(o[df][0] * inv, o[df][1] * inv);
            ov.y = cvt_pk_bf16(o[df][2] * inv, o[df][3] * inv);
            *(uint2*)&ao16[nrow * 128 + hd * 32 + df * 16 + lg * 4] = ov;
        }
    }
}

// ---------------- BN3 finalize + apply: h = sc*t + sh (dual f32 + bf16 write) ----------------
__global__ __launch_bounds__(256) void bn_apply_k(const float* __restrict__ t,
    const float* __restrict__ a3, const float* __restrict__ g3, const float* __restrict__ b3,
    float* __restrict__ h, unsigned short* __restrict__ h16)
{
    __shared__ float sfl[256];
    int tid = threadIdx.x;
    if (tid < 128) {   // identical formula to the old bn_fin_k
        float mean = a3[tid] * (1.f / N_NODES);
        float var  = a3[128 + tid] * (1.f / N_NODES) - mean * mean;
        float sc   = g3[tid] * rsqrtf(var + 1e-5f);
        sfl[tid] = sc;
        sfl[128 + tid] = b3[tid] - mean * sc;
    }
    __syncthreads();
    int idx = blockIdx.x * 256 + tid;
    int cg = (idx & 31) * 4;
    float4 v  = *(const float4*)&t[idx * 4];
    float4 sc = *(const float4*)&sfl[cg];
    float4 sh = *(const float4*)&sfl[128 + cg];
    float4 o;
    o.x = v.x * sc.x + sh.x;
    o.y = v.y * sc.y + sh.y;
    o.z = v.z * sc.z + sh.z;
    o.w = v.w * sc.w + sh.w;
    *(float4*)&h[idx * 4] = o;
    uint2 p;
    p.x = cvt_pk_bf16(o.x, o.y);
    p.y = cvt_pk_bf16(o.z, o.w);
    *(uint2*)&h16[idx * 4] = p;
}

// ---------------- global add pool ----------------
__global__ __launch_bounds__(128) void pool_k(const float* __restrict__ h, float* __restrict__ g)
{
    int b = blockIdx.x, c = threadIdx.x;
    float s = 0.f;
    for (int i = 0; i < NPG; ++i) s += h[(size_t)((b << 9) + i) * C_DIM + c];
    g[b * C_DIM + c] = s;
}

// ---------------- head MLP: [64,128]->64->32->1 ----------------
__global__ __launch_bounds__(256) void head_mlp_k(const float* __restrict__ g,
    const float* __restrict__ w1, const float* __restrict__ b1,
    const float* __restrict__ w2, const float* __restrict__ b2,
    const float* __restrict__ w3, const float* __restrict__ b3,
    float* __restrict__ out)
{
    __shared__ float gs[64 * 128];
    __shared__ float y1[64 * 64];
    __shared__ float y2[64 * 32];
    int tid = threadIdx.x;
    for (int r = 0; r < 32; ++r) gs[r * 256 + tid] = g[r * 256 + tid];
    __syncthreads();
    for (int t = 0; t < 16; ++t) {
        int idx = t * 256 + tid;
        int gi = idx >> 6, c = idx & 63;
        float s = b1[c];
        for (int k = 0; k < 128; ++k) s = fmaf(gs[gi * 128 + k], w1[k * 64 + c], s);
        y1[gi * 64 + c] = fmaxf(s, 0.f);
    }
    __syncthreads();
    for (int t = 0; t < 8; ++t) {
        int idx = t * 256 + tid;
        int gi = idx >> 5, c = idx & 31;
        float s = b2[c];
        for (int k = 0; k < 64; ++k) s = fmaf(y1[gi * 64 + k], w2[k * 32 + c], s);
        y2[gi * 32 + c] = fmaxf(s, 0.f);
    }
    __syncthreads();
    if (tid < 64) {
        float s = b3[0];
        for (int k = 0; k < 32; ++k) s = fmaf(y2[tid * 32 + k], w3[k], s);
        out[tid] = s;
    }
}

extern "C" void kernel_launch(void* const* d_in, const int* in_sizes, int n_in,
                              void* d_out, int out_size, void* d_ws, size_t ws_size,
                              hipStream_t stream)
{
    const int*   x        = (const int*)  d_in[0];
    const float* pe       = (const float*)d_in[1];
    const int*   ei       = (const int*)  d_in[2];
    const int*   eattr    = (const int*)  d_in[3];
    const float* node_emb = (const float*)d_in[5];
    const float* plw      = (const float*)d_in[6];
    const float* plb      = (const float*)d_in[7];
    const float* pe_g     = (const float*)d_in[8];
    const float* pe_b     = (const float*)d_in[9];
    const float* edge_emb = (const float*)d_in[10];
    const float* gw1      = (const float*)d_in[11];
    const float* gb1      = (const float*)d_in[12];
    const float* gw2      = (const float*)d_in[13];
    const float* gb2      = (const float*)d_in[14];
    const float* wqkv     = (const float*)d_in[15];
    const float* bqkv     = (const float*)d_in[16];
    const float* wo       = (const float*)d_in[17];
    const float* bo       = (const float*)d_in[18];
    const float* n1g      = (const float*)d_in[19];
    const float* n1b      = (const float*)d_in[20];
    const float* n2g      = (const float*)d_in[21];
    const float* n2b      = (const float*)d_in[22];
    const float* n3g      = (const float*)d_in[23];
    const float* n3b      = (const float*)d_in[24];
    const float* fw1      = (const float*)d_in[25];
    const float* fb1      = (const float*)d_in[26];
    const float* fw2      = (const float*)d_in[27];
    const float* fb2      = (const float*)d_in[28];
    const float* mw1      = (const float*)d_in[29];
    const float* mb1      = (const float*)d_in[30];
    const float* mw2      = (const float*)d_in[31];
    const float* mb2      = (const float*)d_in[32];
    const float* mw3      = (const float*)d_in[33];
    const float* mb3      = (const float*)d_in[34];

    float* wf  = (float*)d_ws;
    float* Hb  = wf;                                             // h [N,C] f32        [0,1NF)
    unsigned short* Zb16 = (unsigned short*)(wf + (size_t)NF);   // z / attn-out bf16  [1NF,1.5NF)
    float* T1  = wf + 2 * (size_t)NF;                            // t1 / t3 f32        [2NF,3NF)
    unsigned short* QKVb = (unsigned short*)(wf + 3 * (size_t)NF); // qkv bf16 [N,384] [3NF,4.5NF)
    float* T2  = wf + 3 * (size_t)NF;                            // t2 f32 (aliases dead qkv) [3NF,4NF)
    unsigned short* vtg = (unsigned short*)(wf + 4 * (size_t)NF + (size_t)NF / 2); // V^T bf16 [4.5NF,5NF)
    unsigned short* Hb16 = (unsigned short*)(wf + 5 * (size_t)NF); // h bf16 [N,C]     [5NF,5.5NF)
    int* wi     = (int*)(wf + 6 * (size_t)NF);
    int* indptr = wi;                      // N+1
    int* cnt    = wi + 32800;
    int* cnt2   = cnt + N_NODES;
    int* bsum   = cnt2 + N_NODES;          // 128
    int* bpre   = bsum + 128;              // 128
    int* esa    = bpre + 128;              // E packed (src | attr<<16)
    float* st    = (float*)(esa + E_EDGES);
    float* peacc = st;                     // 64
    float* bnacc = st + 64;                // 12*256
    float* gpool = bnacc + 12 * 256;       // 64*128
    short* wT    = (short*)(gpool + 64 * 128);  // 655360 bf16 transposed weights

    const int* srcA = ei;
    const int* dstA = ei + E_EDGES;
    const int LSTR = 163840;

    hipMemsetAsync(peacc, 0, (64 + 12 * 256) * sizeof(float), stream);
    hipMemsetAsync(cnt, 0, 2 * N_NODES * sizeof(int), stream);

    wt_prep_k<<<640, 256, 0, stream>>>(gw1, gw2, wqkv, wo, fw1, fw2, wT);
    pe_stats_k<<<32, 256, 0, stream>>>(pe, peacc);
    h0_k<<<N_NODES / 2, 256, 0, stream>>>(x, pe, node_emb, plw, plb, peacc, pe_g, pe_b, Hb, Hb16);
    hist_k<<<E_EDGES / 256, 256, 0, stream>>>(dstA, cnt);
    bsum_k<<<128, 256, 0, stream>>>(cnt, bsum);
    bscan_k<<<1, 128, 0, stream>>>(bsum, bpre);
    indptr_k<<<128, 256, 0, stream>>>(cnt, bpre, indptr);
    scatter_k<<<E_EDGES / 256, 256, 0, stream>>>(dstA, srcA, eattr, indptr, cnt2, esa);

    for (int l = 0; l < L_LAYERS; ++l) {
        const short* gw1t  = wT + (size_t)l * LSTR;
        const short* gw2t  = wT + (size_t)l * LSTR + 16384;
        const short* wqkvt = wT + (size_t)l * LSTR + 32768;
        const short* wot   = wT + (size_t)l * LSTR + 81920;
        const short* fw1t  = wT + (size_t)l * LSTR + 98304;
        const short* fw2t  = wT + (size_t)l * LSTR + 131072;
        const float* lgb1  = gb1 + (size_t)l * 128;
        const float* lgb2  = gb2 + (size_t)l * 128;
        const float* lbqkv = bqkv + (size_t)l * 384;
        const float* lbo   = bo + (size_t)l * 128;
        const float* lfb1  = fb1 + (size_t)l * 256;
        const float* lfb2  = fb2 + (size_t)l * 128;
        float* acc1 = bnacc + (l * 3 + 0) * 256;
        float* acc2 = bnacc + (l * 3 + 1) * 256;
        float* acc3 = bnacc + (l * 3 + 2) * 256;

        gine_gather_k<<<N_NODES / 4, 256, 0, stream>>>(Hb16, esa, indptr, edge_emb, Zb16);
        gine_mlp_k<<<256, 512, 0, stream>>>(
            Zb16, (const unsigned short*)gw1t, lgb1, (const unsigned short*)gw2t, lgb2,
            Hb, T1, acc1);
        mgemm_k<128, 384, 0, 0, false, false, true,  true, true ><<<dim3(3, 256), 256, 0, stream>>>(
            Hb16, nullptr, nullptr, nullptr, (const unsigned short*)wqkvt, lbqkv,
            nullptr, nullptr, nullptr, nullptr, QKVb, nullptr, vtg);
        attn_mfma_k<<<dim3(8, 4, 64), 256, 0, stream>>>(QKVb, vtg, Zb16);
        mgemm_k<128, 128, 0, 1, false, true,  false, true, false><<<dim3(1, 256), 256, 0, stream>>>(
            Zb16, nullptr, nullptr, nullptr, (const unsigned short*)wot, lbo,
            Hb, nullptr, nullptr, nullptr, T2, acc2, nullptr);
        ffn_mlp_k<<<512, 256, 0, stream>>>(
            T1, T2,
            acc1, n1g + l * 128, n1b + l * 128,
            acc2, n2g + l * 128, n2b + l * 128,
            (const unsigned short*)fw1t, lfb1, (const unsigned short*)fw2t, lfb2,
            T1, acc3);
        bn_apply_k<<<NF / 1024, 256, 0, stream>>>(T1, acc3, n3g + l * 128, n3b + l * 128, Hb, Hb16);
    }
    pool_k<<<B_GR, 128, 0, stream>>>(Hb, gpool);
    head_mlp_k<<<1, 256, 0, stream>>>(gpool, mw1, mb1, mw2, mb2, mw3, mb3, (float*)d_out);
}

// Round 17
// 695.438 us; speedup vs baseline: 1.1017x; 1.0082x over previous
//
#include <hip/hip_runtime.h>
#include <math.h>
#include <cstddef>

#define N_NODES 32768
#define C_DIM   128
#define E_EDGES 262144
#define B_GR    64
#define NPG     512
#define WALK_D  20
#define L_LAYERS 4

static constexpr int NF = N_NODES * C_DIM;  // 4,194,304 floats per [N,C] tensor

typedef __attribute__((ext_vector_type(8))) short bf16x8;
typedef __attribute__((ext_vector_type(4))) float f32x4;
typedef __attribute__((ext_vector_type(4))) short short4v;

__device__ inline unsigned short f2bf(float f)
{
    union { float f; unsigned u; } v; v.f = f;
    unsigned r = v.u + 0x7fff + ((v.u >> 16) & 1);
    return (unsigned short)(r >> 16);
}
__device__ inline float bf2f_lo(unsigned u) { return __uint_as_float(u << 16); }
__device__ inline float bf2f_hi(unsigned u) { return __uint_as_float(u & 0xffff0000u); }
// HW packed bf16 convert (RNE, identical bits to f2bf for normal/denormal finite inputs)
__device__ inline unsigned cvt_pk_bf16(float lo, float hi)
{
    unsigned r;
    asm("v_cvt_pk_bf16_f32 %0, %1, %2" : "=v"(r) : "v"(lo), "v"(hi));
    return r;
}

// ---------------- merged setup A: wt_prep (640) + pe_stats (32) + hist (1024) ----------------
__global__ __launch_bounds__(256) void setup_a_k(
    const float* __restrict__ gw1, const float* __restrict__ gw2,
    const float* __restrict__ wqkv, const float* __restrict__ wo,
    const float* __restrict__ fw1, const float* __restrict__ fw2,
    short* __restrict__ out,
    const float* __restrict__ pe, float* __restrict__ acc,
    const int* __restrict__ dst, int* __restrict__ cnt)
{
    __shared__ float ts[32][36];
    const int b = blockIdx.x;
    const int tid = threadIdx.x;
    if (b < 640) {
        int l = b / 160, t = b % 160;
        const float* src; int K, N; size_t obase; int tile;
        if (t < 16)       { src = gw1  + (size_t)l * 16384; K = 128; N = 128; obase = (size_t)l * 163840 + 0;      tile = t; }
        else if (t < 32)  { src = gw2  + (size_t)l * 16384; K = 128; N = 128; obase = (size_t)l * 163840 + 16384;  tile = t - 16; }
        else if (t < 80)  { src = wqkv + (size_t)l * 49152; K = 128; N = 384; obase = (size_t)l * 163840 + 32768;  tile = t - 32; }
        else if (t < 96)  { src = wo   + (size_t)l * 16384; K = 128; N = 128; obase = (size_t)l * 163840 + 81920;  tile = t - 80; }
        else if (t < 128) { src = fw1  + (size_t)l * 32768; K = 128; N = 256; obase = (size_t)l * 163840 + 98304;  tile = t - 96; }
        else              { src = fw2  + (size_t)l * 32768; K = 256; N = 128; obase = (size_t)l * 163840 + 131072; tile = t - 128; }
        int ntN = N / 32;
        int tk = tile / ntN, tn = tile % ntN;
        int r = tid >> 3, c4 = (tid & 7) * 4;
        *(float4*)&ts[r][c4] = *(const float4*)&src[(size_t)(tk * 32 + r) * N + tn * 32 + c4];
        __syncthreads();
        int n = tid >> 3, k4 = (tid & 7) * 4;
        short4v pk;
        #pragma unroll
        for (int i2 = 0; i2 < 4; ++i2) pk[i2] = (short)f2bf(ts[k4 + i2][n]);
        *(short4v*)&out[obase + (size_t)(tn * 32 + n) * K + tk * 32 + k4] = pk;
    } else if (b < 672) {
        int gt = (b - 640) * 256 + tid;
        float s[WALK_D], q[WALK_D];
        #pragma unroll
        for (int c = 0; c < WALK_D; ++c) { s[c] = 0.f; q[c] = 0.f; }
        for (int r = 0; r < 4; ++r) {
            const float* row = &pe[(size_t)(gt + r * 8192) * WALK_D];
            float v[20];
            #pragma unroll
            for (int j = 0; j < 5; ++j) *(float4*)&v[j * 4] = *(const float4*)(row + j * 4);
            #pragma unroll
            for (int c = 0; c < WALK_D; ++c) { s[c] += v[c]; q[c] += v[c] * v[c]; }
        }
        #pragma unroll
        for (int c = 0; c < WALK_D; ++c) {
            float ss = s[c], qq = q[c];
            #pragma unroll
            for (int m = 1; m < 64; m <<= 1) { ss += __shfl_xor(ss, m); qq += __shfl_xor(qq, m); }
            if ((tid & 63) == 0) { atomicAdd(&acc[c], ss); atomicAdd(&acc[32 + c], qq); }
        }
    } else {
        int e = (b - 672) * 256 + tid;
        atomicAdd(&cnt[dst[e]], 1);
    }
}

// ---------------- CSR scan chain ----------------
__global__ __launch_bounds__(256) void bsum_k(const int* __restrict__ cnt, int* __restrict__ bsum)
{
    __shared__ int ws[4];
    int b = blockIdx.x, t = threadIdx.x;
    int v = cnt[b * 256 + t];
    #pragma unroll
    for (int m = 1; m < 64; m <<= 1) v += __shfl_xor(v, m);
    if ((t & 63) == 0) ws[t >> 6] = v;
    __syncthreads();
    if (t == 0) bsum[b] = ws[0] + ws[1] + ws[2] + ws[3];
}

__global__ __launch_bounds__(128) void bscan_k(const int* __restrict__ bsum, int* __restrict__ bpre)
{
    __shared__ int s[128];
    int t = threadIdx.x;
    int v = bsum[t];
    s[t] = v;
    __syncthreads();
    for (int off = 1; off < 128; off <<= 1) {
        int u = (t >= off) ? s[t - off] : 0;
        __syncthreads();
        s[t] += u;
        __syncthreads();
    }
    bpre[t] = s[t] - v;
}

__global__ __launch_bounds__(256) void indptr_k(const int* __restrict__ cnt, const int* __restrict__ bpre,
                                                int* __restrict__ indptr)
{
    __shared__ int s[256];
    int b = blockIdx.x, t = threadIdx.x;
    int v = cnt[b * 256 + t];
    s[t] = v;
    __syncthreads();
    for (int off = 1; off < 256; off <<= 1) {
        int u = (t >= off) ? s[t - off] : 0;
        __syncthreads();
        s[t] += u;
        __syncthreads();
    }
    indptr[b * 256 + t] = bpre[b] + s[t] - v;
    if (b == 127 && t == 255) indptr[N_NODES] = E_EDGES;
}

// ---------------- merged setup B: scatter+esa (1024) + h0 (16384) ----------------
__global__ __launch_bounds__(256) void setup_b_k(
    const int* __restrict__ dst, const int* __restrict__ src, const int* __restrict__ attr,
    const int* __restrict__ indptr, int* __restrict__ cur, int* __restrict__ esa,
    const int* __restrict__ x, const float* __restrict__ pe,
    const float* __restrict__ node_emb, const float* __restrict__ plw, const float* __restrict__ plb,
    const float* __restrict__ peacc, const float* __restrict__ pe_g, const float* __restrict__ pe_b,
    float* __restrict__ h, unsigned short* __restrict__ h16)
{
    __shared__ float spe[64];
    const int b = blockIdx.x;
    const int tid = threadIdx.x;
    if (b < 1024) {
        int e = b * 256 + tid;
        int d = dst[e];
        int pos = atomicAdd(&cur[d], 1);
        esa[indptr[d] + pos] = src[e] | (attr[e] << 16);
    } else {
        if (tid < WALK_D) {
            float mean = peacc[tid] * (1.f / N_NODES);
            float var  = peacc[32 + tid] * (1.f / N_NODES) - mean * mean;
            float sc   = pe_g[tid] * rsqrtf(var + 1e-5f);
            spe[tid] = sc;
            spe[32 + tid] = pe_b[tid] - mean * sc;
        }
        __syncthreads();
        int i = (b - 1024) * 2 + (tid >> 7);
        int c = tid & 127;
        float v;
        if (c < 120) {
            v = node_emb[x[i] * 120 + c];
        } else {
            int pc = c - 120;
            v = plb[pc];
            #pragma unroll
            for (int k = 0; k < WALK_D; ++k) {
                float pn = pe[i * WALK_D + k] * spe[k] + spe[32 + k];
                v = fmaf(pn, plw[k * 8 + pc], v);
            }
        }
        h[i * C_DIM + c] = v;
        h16[i * C_DIM + c] = f2bf(v);
    }
}

// ---------------- GINE message aggregation (bf16 in/out): z = h + sum_in relu(h[src]+ee) ----------------
__global__ __launch_bounds__(256) void gine_gather_k(const unsigned short* __restrict__ h16,
    const int* __restrict__ esa, const int* __restrict__ indptr,
    const float* __restrict__ edge_emb, unsigned short* __restrict__ z16)
{
    __shared__ float ee[4 * C_DIM];
    int tid = threadIdx.x;
    ee[tid] = edge_emb[tid];
    ee[tid + 256] = edge_emb[tid + 256];
    __syncthreads();
    int i = blockIdx.x * 4 + (tid >> 6);
    int c = (tid & 63) * 2;
    int p0 = indptr[i], p1 = indptr[i + 1];
    float s0 = 0.f, s1 = 0.f;
    int p = p0;
    for (; p + 4 <= p1; p += 4) {
        int sa0 = esa[p], sa1 = esa[p + 1], sa2 = esa[p + 2], sa3 = esa[p + 3];
        unsigned u0 = *(const unsigned*)&h16[(size_t)(sa0 & 0xffff) * C_DIM + c];
        unsigned u1 = *(const unsigned*)&h16[(size_t)(sa1 & 0xffff) * C_DIM + c];
        unsigned u2 = *(const unsigned*)&h16[(size_t)(sa2 & 0xffff) * C_DIM + c];
        unsigned u3 = *(const unsigned*)&h16[(size_t)(sa3 & 0xffff) * C_DIM + c];
        float2 e0 = *(const float2*)&ee[(sa0 >> 16) * C_DIM + c];
        float2 e1 = *(const float2*)&ee[(sa1 >> 16) * C_DIM + c];
        float2 e2 = *(const float2*)&ee[(sa2 >> 16) * C_DIM + c];
        float2 e3 = *(const float2*)&ee[(sa3 >> 16) * C_DIM + c];
        s0 += fmaxf(bf2f_lo(u0) + e0.x, 0.f); s1 += fmaxf(bf2f_hi(u0) + e0.y, 0.f);
        s0 += fmaxf(bf2f_lo(u1) + e1.x, 0.f); s1 += fmaxf(bf2f_hi(u1) + e1.y, 0.f);
        s0 += fmaxf(bf2f_lo(u2) + e2.x, 0.f); s1 += fmaxf(bf2f_hi(u2) + e2.y, 0.f);
        s0 += fmaxf(bf2f_lo(u3) + e3.x, 0.f); s1 += fmaxf(bf2f_hi(u3) + e3.y, 0.f);
    }
    for (; p < p1; ++p) {
        int sa = esa[p];
        unsigned u = *(const unsigned*)&h16[(size_t)(sa & 0xffff) * C_DIM + c];
        float2 ev = *(const float2*)&ee[(sa >> 16) * C_DIM + c];
        s0 += fmaxf(bf2f_lo(u) + ev.x, 0.f);
        s1 += fmaxf(bf2f_hi(u) + ev.y, 0.f);
    }
    unsigned us = *(const unsigned*)&h16[(size_t)i * C_DIM + c];
    s0 += bf2f_lo(us);
    s1 += bf2f_hi(us);
    *(unsigned*)&z16[(size_t)i * C_DIM + c] = cvt_pk_bf16(s0, s1);
}

// ---------------- MFMA bf16 GEMM (B staged in 64-col halves; 48KB LDS -> 3 blocks/CU) ----------------
// VOUT: for the qkv GEMM, col-block at col0==256 (the V part) writes the pre-swizzled
// vtg image directly instead of Cout. Per-output MFMA order identical to the full-B version.
template<int KD, int NC, int AMODE, int RESMODE, bool RELU, bool STATS, bool OUTBF, bool ABF, bool VOUT>
__global__ __launch_bounds__(256) void mgemm_k(
    const void* __restrict__ Av, const float* __restrict__ A2,
    const float* __restrict__ affA1, const float* __restrict__ affA2,
    const unsigned short* __restrict__ Bt, const float* __restrict__ bias,
    const float* __restrict__ R1, const float* __restrict__ R2,
    const float* __restrict__ affR1, const float* __restrict__ affR2,
    void* __restrict__ Cout, float* __restrict__ stats,
    unsigned short* __restrict__ vtg)
{
    __shared__ short As[16384];   // [128 rows][128 k] bf16, XOR-swizzled granules
    __shared__ short Bs[8192];    // [64 cols][128 k] bf16 (current half)
    const int tid = threadIdx.x;
    const int w = tid >> 6;
    const int lane = tid & 63;
    const int lr = lane & 15, lg = lane >> 4;
    const int row0 = blockIdx.y * 128;
    const int col0 = blockIdx.x * 128;

    const f32x4 zero = {0.f, 0.f, 0.f, 0.f};
    f32x4 acc[2][8];
    #pragma unroll
    for (int i = 0; i < 2; ++i)
        #pragma unroll
        for (int cf = 0; cf < 8; ++cf) acc[i][cf] = zero;

    for (int kt = 0; kt < KD / 128; ++kt) {
        if (kt > 0) __syncthreads();
        #pragma unroll
        for (int it = 0; it < 8; ++it) {
            int gid = it * 256 + tid;
            int row = gid >> 4, g = gid & 15;
            bf16x8 pk;
            if (ABF) {
                pk = *(const bf16x8*)&((const unsigned short*)Av)[(size_t)(row0 + row) * KD + kt * 128 + g * 8];
            } else {
                const float* Af = (const float*)Av;
                const float* ap = &Af[(size_t)(row0 + row) * KD + kt * 128 + g * 8];
                float v[8];
                *(float4*)&v[0] = *(const float4*)ap;
                *(float4*)&v[4] = *(const float4*)(ap + 4);
                if (AMODE == 1) {
                    const float* ap2 = &A2[(size_t)(row0 + row) * KD + kt * 128 + g * 8];
                    float u[8];
                    *(float4*)&u[0] = *(const float4*)ap2;
                    *(float4*)&u[4] = *(const float4*)(ap2 + 4);
                    #pragma unroll
                    for (int j = 0; j < 8; ++j) {
                        int ck = g * 8 + j;
                        v[j] = v[j] * affA1[ck] + affA1[128 + ck] + u[j] * affA2[ck] + affA2[128 + ck];
                    }
                }
                #pragma unroll
                for (int j = 0; j < 8; ++j) pk[j] = (short)f2bf(v[j]);
            }
            *(bf16x8*)&As[(row * 16 + (g ^ (row & 7))) * 8] = pk;
        }
        #pragma unroll
        for (int h = 0; h < 2; ++h) {
            if (h > 0) __syncthreads();   // prior Bs reads done
            #pragma unroll
            for (int it = 0; it < 4; ++it) {
                int gid = it * 256 + tid;
                int row = gid >> 4, g = gid & 15;   // row = local B col in half
                bf16x8 bv = *(const bf16x8*)&Bt[(size_t)(col0 + h * 64 + row) * KD + kt * 128 + g * 8];
                *(bf16x8*)&Bs[(row * 16 + (g ^ (row & 7))) * 8] = bv;
            }
            __syncthreads();
            #pragma unroll
            for (int ks = 0; ks < 4; ++ks) {
                bf16x8 af[2], bfr[4];
                #pragma unroll
                for (int i = 0; i < 2; ++i) {
                    int row = w * 32 + i * 16 + lr;
                    int g = ks * 4 + lg;
                    af[i] = *(const bf16x8*)&As[(row * 16 + (g ^ (row & 7))) * 8];
                }
                #pragma unroll
                for (int cfl = 0; cfl < 4; ++cfl) {
                    int lc = cfl * 16 + lr;   // local col in half; (col&7)==(lc&7)
                    int g = ks * 4 + lg;
                    bfr[cfl] = *(const bf16x8*)&Bs[(lc * 16 + (g ^ (lc & 7))) * 8];
                }
                #pragma unroll
                for (int i = 0; i < 2; ++i)
                    #pragma unroll
                    for (int cfl = 0; cfl < 4; ++cfl)
                        acc[i][h * 4 + cfl] = __builtin_amdgcn_mfma_f32_16x16x32_bf16(af[i], bfr[cfl], acc[i][h * 4 + cfl], 0, 0, 0);
            }
        }
    }

    float* cs = (float*)As;       // alias LDS after compute
    float* cq = cs + 128;
    if (STATS) {
        __syncthreads();
        if (tid < 128) { cs[tid] = 0.f; cq[tid] = 0.f; }
        __syncthreads();
    }
    float bs_v[8];
    #pragma unroll
    for (int cf = 0; cf < 8; ++cf) bs_v[cf] = bias[col0 + cf * 16 + lr];
    float rs1[8], ro1[8], rs2[8], ro2[8];
    if (RESMODE == 2) {
        #pragma unroll
        for (int cf = 0; cf < 8; ++cf) {
            int c = cf * 16 + lr;
            rs1[cf] = affR1[c]; ro1[cf] = affR1[128 + c];
            rs2[cf] = affR2[c]; ro2[cf] = affR2[128 + c];
        }
    }
    float colS[8], colQ[8];
    #pragma unroll
    for (int cf = 0; cf < 8; ++cf) { colS[cf] = 0.f; colQ[cf] = 0.f; }
    const bool vblk = VOUT && (col0 == 256);
    #pragma unroll
    for (int i = 0; i < 2; ++i) {
        #pragma unroll
        for (int r = 0; r < 4; ++r) {
            size_t grow = row0 + w * 32 + i * 16 + lg * 4 + r;
            #pragma unroll
            for (int cf = 0; cf < 8; ++cf) {
                int c = col0 + cf * 16 + lr;
                float val = acc[i][cf][r] + bs_v[cf];
                if (RESMODE == 1) val += R1[grow * NC + c];
                if (RESMODE == 2) {
                    val += R1[grow * 128 + c] * rs1[cf] + ro1[cf]
                         + R2[grow * 128 + c] * rs2[cf] + ro2[cf];
                }
                if (RELU) val = fmaxf(val, 0.f);
                if (VOUT && vblk) {
                    int g2 = (int)(grow >> 9);
                    int key = (int)(grow & 511);
                    int kc = key >> 6, kg = (key >> 3) & 7, j = key & 7;
                    int cd = c - 256;
                    int hd2 = cd >> 5, dd = cd & 31;
                    vtg[((size_t)(g2 * 4 + hd2) * 8 + kc) * 2048 + dd * 64 + ((kg ^ (dd & 7)) << 3) + j] = f2bf(val);
                } else if (OUTBF) {
                    ((unsigned short*)Cout)[grow * NC + c] = f2bf(val);
                } else {
                    ((float*)Cout)[grow * NC + c] = val;
                }
                if (STATS) { colS[cf] += val; colQ[cf] += val * val; }
            }
        }
    }
    if (STATS) {
        #pragma unroll
        for (int cf = 0; cf < 8; ++cf) {
            float s = colS[cf], q = colQ[cf];
            s += __shfl_xor(s, 16); s += __shfl_xor(s, 32);
            q += __shfl_xor(q, 16); q += __shfl_xor(q, 32);
            if (lg == 0) { atomicAdd(&cs[cf * 16 + lr], s); atomicAdd(&cq[cf * 16 + lr], q); }
        }
        __syncthreads();
        if (tid < 128) {
            atomicAdd(&stats[tid], cs[tid]);
            atomicAdd(&stats[128 + tid], cq[tid]);
        }
    }
}

// ---------------- fused GINE MLP, 512 threads / 8 waves, 128-row tile ----------------
__global__ __launch_bounds__(512) void gine_mlp_k(
    const unsigned short* __restrict__ z16,
    const unsigned short* __restrict__ W1t, const float* __restrict__ b1,
    const unsigned short* __restrict__ W2t, const float* __restrict__ b2,
    const float* __restrict__ Hres,
    float* __restrict__ T1out, float* __restrict__ stats)
{
    __shared__ short As[16384];
    __shared__ short Bs[16384];
    const int tid = threadIdx.x;
    const int w = tid >> 6;          // 0..7
    const int lane = tid & 63;
    const int lr = lane & 15, lg = lane >> 4;
    const int row0 = blockIdx.x * 128;
    const f32x4 zero = {0.f, 0.f, 0.f, 0.f};
    const int arow = w * 16 + lr;

    #pragma unroll
    for (int it = 0; it < 4; ++it) {
        int gid = it * 512 + tid;
        int row = gid >> 4, g = gid & 15;
        bf16x8 av = *(const bf16x8*)&z16[(size_t)(row0 + row) * 128 + g * 8];
        *(bf16x8*)&As[(row * 16 + (g ^ (row & 7))) * 8] = av;
        bf16x8 bv = *(const bf16x8*)&W1t[(size_t)row * 128 + g * 8];
        *(bf16x8*)&Bs[(row * 16 + (g ^ (row & 7))) * 8] = bv;
    }
    __syncthreads();

    f32x4 acc[8];
    #pragma unroll
    for (int cf = 0; cf < 8; ++cf) acc[cf] = zero;
    #pragma unroll
    for (int ks = 0; ks < 4; ++ks) {
        int g = ks * 4 + lg;
        bf16x8 af = *(const bf16x8*)&As[(arow * 16 + (g ^ (arow & 7))) * 8];
        #pragma unroll
        for (int cf = 0; cf < 8; ++cf) {
            int c = cf * 16 + lr;
            bf16x8 bfr = *(const bf16x8*)&Bs[(c * 16 + (g ^ (c & 7))) * 8];
            acc[cf] = __builtin_amdgcn_mfma_f32_16x16x32_bf16(af, bfr, acc[cf], 0, 0, 0);
        }
    }
    __syncthreads();   // all As(z)/Bs(W1) reads complete

    {   // Y = f2bf(relu(acc + b1)) -> As (same swizzled positions & rounding point)
        float bias1[8];
        #pragma unroll
        for (int cf = 0; cf < 8; ++cf) bias1[cf] = b1[cf * 16 + lr];
        #pragma unroll
        for (int r = 0; r < 4; ++r) {
            int row = w * 16 + lg * 4 + r;
            #pragma unroll
            for (int cf = 0; cf < 8; ++cf) {
                int col = cf * 16 + lr;
                float val = fmaxf(acc[cf][r] + bias1[cf], 0.f);
                As[(row * 16 + ((col >> 3) ^ (row & 7))) * 8 + (col & 7)] = (short)f2bf(val);
            }
        }
    }
    #pragma unroll
    for (int it = 0; it < 4; ++it) {
        int gid = it * 512 + tid;
        int row = gid >> 4, g = gid & 15;
        bf16x8 bv = *(const bf16x8*)&W2t[(size_t)row * 128 + g * 8];
        *(bf16x8*)&Bs[(row * 16 + (g ^ (row & 7))) * 8] = bv;
    }
    __syncthreads();

    #pragma unroll
    for (int cf = 0; cf < 8; ++cf) acc[cf] = zero;
    #pragma unroll
    for (int ks = 0; ks < 4; ++ks) {
        int g = ks * 4 + lg;
        bf16x8 af = *(const bf16x8*)&As[(arow * 16 + (g ^ (arow & 7))) * 8];
        #pragma unroll
        for (int cf = 0; cf < 8; ++cf) {
            int c = cf * 16 + lr;
            bf16x8 bfr = *(const bf16x8*)&Bs[(c * 16 + (g ^ (c & 7))) * 8];
            acc[cf] = __builtin_amdgcn_mfma_f32_16x16x32_bf16(af, bfr, acc[cf], 0, 0, 0);
        }
    }

    float* cs = (float*)As;
    float* cq = cs + 128;
    __syncthreads();
    if (tid < 128) { cs[tid] = 0.f; cq[tid] = 0.f; }
    __syncthreads();
    float bs_v[8];
    #pragma unroll
    for (int cf = 0; cf < 8; ++cf) bs_v[cf] = b2[cf * 16 + lr];
    float colS[8], colQ[8];
    #pragma unroll
    for (int cf = 0; cf < 8; ++cf) { colS[cf] = 0.f; colQ[cf] = 0.f; }
    #pragma unroll
    for (int r = 0; r < 4; ++r) {
        size_t grow = row0 + w * 16 + lg * 4 + r;
        #pragma unroll
        for (int cf = 0; cf < 8; ++cf) {
            int c = cf * 16 + lr;
            float val = acc[cf][r] + bs_v[cf] + Hres[grow * 128 + c];
            T1out[grow * 128 + c] = val;
            colS[cf] += val; colQ[cf] += val * val;
        }
    }
    #pragma unroll
    for (int cf = 0; cf < 8; ++cf) {
        float s = colS[cf], q = colQ[cf];
        s += __shfl_xor(s, 16); s += __shfl_xor(s, 32);
        q += __shfl_xor(q, 16); q += __shfl_xor(q, 32);
        if (lg == 0) { atomicAdd(&cs[cf * 16 + lr], s); atomicAdd(&cq[cf * 16 + lr], q); }
    }
    __syncthreads();
    if (tid < 128) {
        atomicAdd(&stats[tid], cs[tid]);
        atomicAdd(&stats[128 + tid], cq[tid]);
    }
}

// ---------------- fused FFN (+ BN1/BN2 finalize in prologue): T1 = FFN(...) + aff(T1,T2), BN3 stats ----
__global__ __launch_bounds__(256) void ffn_mlp_k(
    const float* __restrict__ T1, const float* __restrict__ T2,
    const float* __restrict__ a1, const float* __restrict__ g1v, const float* __restrict__ b1v,
    const float* __restrict__ a2, const float* __restrict__ g2v, const float* __restrict__ b2v,
    const unsigned short* __restrict__ W1t, const float* __restrict__ fb1,
    const unsigned short* __restrict__ W2t, const float* __restrict__ fb2,
    float* __restrict__ T1out, float* __restrict__ stats)
{
    __shared__ short As[8192];    // [64 rows][128 k]
    __shared__ short Bs[16384];   // [128][128] (W1 col-half / W2 k-half)
    __shared__ short Ys[8192];    // [64 rows][128 hidden] current half
    __shared__ float sf1l[256], sf2l[256];
    const int tid = threadIdx.x;
    const int w = tid >> 6;
    const int lane = tid & 63;
    const int lr = lane & 15, lg = lane >> 4;
    const int row0 = blockIdx.x * 64;
    const f32x4 zero = {0.f, 0.f, 0.f, 0.f};

    if (tid < 128) {   // BN1/BN2 finalize (identical formula to the old bn_fin_k)
        float mean = a1[tid] * (1.f / N_NODES);
        float var  = a1[128 + tid] * (1.f / N_NODES) - mean * mean;
        float sc   = g1v[tid] * rsqrtf(var + 1e-5f);
        sf1l[tid] = sc; sf1l[128 + tid] = b1v[tid] - mean * sc;
        mean = a2[tid] * (1.f / N_NODES);
        var  = a2[128 + tid] * (1.f / N_NODES) - mean * mean;
        sc   = g2v[tid] * rsqrtf(var + 1e-5f);
        sf2l[tid] = sc; sf2l[128 + tid] = b2v[tid] - mean * sc;
    }
    __syncthreads();

    #pragma unroll
    for (int it = 0; it < 4; ++it) {
        int gid = it * 256 + tid;
        int row = gid >> 4, g = gid & 15;
        const float* ap = &T1[(size_t)(row0 + row) * 128 + g * 8];
        const float* ap2 = &T2[(size_t)(row0 + row) * 128 + g * 8];
        float v[8], u[8];
        *(float4*)&v[0] = *(const float4*)ap;
        *(float4*)&v[4] = *(const float4*)(ap + 4);
        *(float4*)&u[0] = *(const float4*)ap2;
        *(float4*)&u[4] = *(const float4*)(ap2 + 4);
        unsigned pw[4];
        #pragma unroll
        for (int j2 = 0; j2 < 4; ++j2) {
            int ck0 = g * 8 + j2 * 2, ck1 = ck0 + 1;
            float x0 = v[j2 * 2]     * sf1l[ck0] + sf1l[128 + ck0] + u[j2 * 2]     * sf2l[ck0] + sf2l[128 + ck0];
            float x1 = v[j2 * 2 + 1] * sf1l[ck1] + sf1l[128 + ck1] + u[j2 * 2 + 1] * sf2l[ck1] + sf2l[128 + ck1];
            pw[j2] = cvt_pk_bf16(x0, x1);
        }
        *(uint4*)&As[(row * 16 + (g ^ (row & 7))) * 8] = *(uint4*)pw;
    }

    f32x4 acc2[8];
    #pragma unroll
    for (int cf = 0; cf < 8; ++cf) acc2[cf] = zero;

    const int arow = w * 16 + lr;
    for (int h = 0; h < 2; ++h) {
        if (h > 0) __syncthreads();
        #pragma unroll
        for (int it = 0; it < 8; ++it) {
            int gid = it * 256 + tid;
            int row = gid >> 4, g = gid & 15;
            bf16x8 bv = *(const bf16x8*)&W1t[(size_t)(h * 128 + row) * 128 + g * 8];
            *(bf16x8*)&Bs[(row * 16 + (g ^ (row & 7))) * 8] = bv;
        }
        __syncthreads();
        f32x4 accY[8];
        #pragma unroll
        for (int cf = 0; cf < 8; ++cf) accY[cf] = zero;
        #pragma unroll
        for (int ks = 0; ks < 4; ++ks) {
            int g = ks * 4 + lg;
            bf16x8 af = *(const bf16x8*)&As[(arow * 16 + (g ^ (arow & 7))) * 8];
            #pragma unroll
            for (int cf = 0; cf < 8; ++cf) {
                int c = cf * 16 + lr;
                bf16x8 bfr = *(const bf16x8*)&Bs[(c * 16 + (g ^ (c & 7))) * 8];
                accY[cf] = __builtin_amdgcn_mfma_f32_16x16x32_bf16(af, bfr, accY[cf], 0, 0, 0);
            }
        }
        __syncthreads();
        #pragma unroll
        for (int r = 0; r < 4; ++r) {
            int row = w * 16 + lg * 4 + r;
            #pragma unroll
            for (int cf = 0; cf < 8; ++cf) {
                int col = cf * 16 + lr;
                float val = fmaxf(accY[cf][r] + fb1[h * 128 + col], 0.f);
                Ys[(row * 16 + ((col >> 3) ^ (row & 7))) * 8 + (col & 7)] = (short)f2bf(val);
            }
        }
        #pragma unroll
        for (int it = 0; it < 8; ++it) {
            int gid = it * 256 + tid;
            int row = gid >> 4, g = gid & 15;
            bf16x8 bv = *(const bf16x8*)&W2t[(size_t)row * 256 + h * 128 + g * 8];
            *(bf16x8*)&Bs[(row * 16 + (g ^ (row & 7))) * 8] = bv;
        }
        __syncthreads();
        #pragma unroll
        for (int ks = 0; ks < 4; ++ks) {
            int g = ks * 4 + lg;
            bf16x8 af = *(const bf16x8*)&Ys[(arow * 16 + (g ^ (arow & 7))) * 8];
            #pragma unroll
            for (int cf = 0; cf < 8; ++cf) {
                int c = cf * 16 + lr;
                bf16x8 bfr = *(const bf16x8*)&Bs[(c * 16 + (g ^ (c & 7))) * 8];
                acc2[cf] = __builtin_amdgcn_mfma_f32_16x16x32_bf16(af, bfr, acc2[cf], 0, 0, 0);
            }
        }
    }

    float* cs = (float*)As;
    float* cq = cs + 128;
    __syncthreads();
    if (tid < 128) { cs[tid] = 0.f; cq[tid] = 0.f; }
    __syncthreads();
    float bs_v[8], rs1[8], ro1[8], rs2[8], ro2[8];
    #pragma unroll
    for (int cf = 0; cf < 8; ++cf) {
        int c = cf * 16 + lr;
        bs_v[cf] = fb2[c];
        rs1[cf] = sf1l[c]; ro1[cf] = sf1l[128 + c];
        rs2[cf] = sf2l[c]; ro2[cf] = sf2l[128 + c];
    }
    float colS[8], colQ[8];
    #pragma unroll
    for (int cf = 0; cf < 8; ++cf) { colS[cf] = 0.f; colQ[cf] = 0.f; }
    #pragma unroll
    for (int r = 0; r < 4; ++r) {
        size_t grow = row0 + w * 16 + lg * 4 + r;
        #pragma unroll
        for (int cf = 0; cf < 8; ++cf) {
            int c = cf * 16 + lr;
            float val = acc2[cf][r] + bs_v[cf]
                      + T1[grow * 128 + c] * rs1[cf] + ro1[cf]
                      + T2[grow * 128 + c] * rs2[cf] + ro2[cf];
            T1out[grow * 128 + c] = val;
            colS[cf] += val; colQ[cf] += val * val;
        }
    }
    #pragma unroll
    for (int cf = 0; cf < 8; ++cf) {
        float s = colS[cf], q = colQ[cf];
        s += __shfl_xor(s, 16); s += __shfl_xor(s, 32);
        q += __shfl_xor(q, 16); q += __shfl_xor(q, 32);
        if (lg == 0) { atomicAdd(&cs[cf * 16 + lr], s); atomicAdd(&cq[cf * 16 + lr], q); }
    }
    __syncthreads();
    if (tid < 128) {
        atomicAdd(&stats[tid], cs[tid]);
        atomicAdd(&stats[128 + tid], cq[tid]);
    }
}

// ---------------- MFMA flash attention, swapped-QK core, 64 q/block (bitwise-identical) ----------------
__global__ __launch_bounds__(256) void attn_mfma_k(const unsigned short* __restrict__ qkvb,
                                                   const unsigned short* __restrict__ vtg,
                                                   unsigned short* __restrict__ ao16)
{
    __shared__ short Qs[2048];      // [64 q][4 dg ^swz][8]
    __shared__ short Ks[2][2048];   // [64 k][4 dg ^swz][8], double-buffered
    __shared__ short Vs[2][2048];   // pre-swizzled V^T image, double-buffered
    __shared__ short Ps[4][1024];   // per-wave P^T [16 q][8 kgran ^swz][8]
    const int tid = threadIdx.x;
    const int w = tid >> 6, lane = tid & 63;
    const int lr = lane & 15, lg = lane >> 4;
    const int q0 = blockIdx.x * 64;
    const int hd = blockIdx.y;
    const int base = blockIdx.z * NPG;
    const float SCL = 0.17677669529663687f * 1.44269504089f;  // 1/sqrt(32) * log2(e)
    const f32x4 zero = {0.f, 0.f, 0.f, 0.f};
    const unsigned short* vbase = vtg + (size_t)(blockIdx.z * 4 + hd) * 16384;

    {   // stage Q (64 rows) + chunk 0 of K/V
        int row = tid >> 2, g = tid & 3;
        bf16x8 qv = *(const bf16x8*)&qkvb[(size_t)(base + q0 + row) * 384 + hd * 32 + g * 8];
        *(bf16x8*)&Qs[(row * 4 + (g ^ ((row >> 1) & 3))) * 8] = qv;
        bf16x8 kv = *(const bf16x8*)&qkvb[(size_t)(base + row) * 384 + 128 + hd * 32 + g * 8];
        *(bf16x8*)&Ks[0][(row * 4 + (g ^ ((row >> 1) & 3))) * 8] = kv;
        bf16x8 vv = *(const bf16x8*)&vbase[tid * 8];
        *(bf16x8*)&Vs[0][tid * 8] = vv;
    }
    __syncthreads();
    const int qrow = w * 16 + lr;
    const bf16x8 bq = *(const bf16x8*)&Qs[(qrow * 4 + (lg ^ ((qrow >> 1) & 3))) * 8];
    float m = -1e30f, lsum = 0.f;
    f32x4 o[2];
    o[0] = zero; o[1] = zero;

    for (int kc = 0; kc < 8; ++kc) {
        int buf = kc & 1;
        bf16x8 knx, vnx;
        if (kc < 7) {   // issue next-chunk loads early, LDS-write late
            int row = tid >> 2, g = tid & 3;
            knx = *(const bf16x8*)&qkvb[(size_t)(base + (kc + 1) * 64 + row) * 384 + 128 + hd * 32 + g * 8];
            vnx = *(const bf16x8*)&vbase[(size_t)(kc + 1) * 2048 + tid * 8];
        }
        bf16x8 ka[4], va[2][2];
        #pragma unroll
        for (int kf = 0; kf < 4; ++kf) {
            int kr = kf * 16 + lr;
            ka[kf] = *(const bf16x8*)&Ks[buf][(kr * 4 + (lg ^ ((kr >> 1) & 3))) * 8];
        }
        #pragma unroll
        for (int ks = 0; ks < 2; ++ks)
            #pragma unroll
            for (int df = 0; df < 2; ++df) {
                int d = df * 16 + lr;
                int kg = ks * 4 + lg;
                va[ks][df] = *(const bf16x8*)&Vs[buf][(d * 8 + (kg ^ (d & 7))) * 8];
            }
        f32x4 s[4];
        #pragma unroll
        for (int kf = 0; kf < 4; ++kf)
            s[kf] = __builtin_amdgcn_mfma_f32_16x16x32_bf16(ka[kf], bq, zero, 0, 0, 0);
        float v[16];
        #pragma unroll
        for (int kf = 0; kf < 4; ++kf)
            #pragma unroll
            for (int r = 0; r < 4; ++r) v[kf * 4 + r] = s[kf][r] * SCL;
        float rm = fmaxf(fmaxf(fmaxf(fmaxf(v[0], v[1]), fmaxf(v[2], v[3])),
                               fmaxf(fmaxf(v[4], v[5]), fmaxf(v[6], v[7]))),
                         fmaxf(fmaxf(fmaxf(v[8], v[9]), fmaxf(v[10], v[11])),
                               fmaxf(fmaxf(v[12], v[13]), fmaxf(v[14], v[15]))));
        rm = fmaxf(rm, __shfl_xor(rm, 16));
        rm = fmaxf(rm, __shfl_xor(rm, 32));
        float mn = fmaxf(m, rm);
        float alpha = exp2f(m - mn);
        float p[16];
        #pragma unroll
        for (int i = 0; i < 16; ++i) p[i] = exp2f(v[i] - mn);
        float S0 = ((p[0] + p[4]) + p[8]) + p[12];
        float S1 = ((p[1] + p[5]) + p[9]) + p[13];
        float S2 = ((p[2] + p[6]) + p[10]) + p[14];
        float S3 = ((p[3] + p[7]) + p[11]) + p[15];
        float ps = (S0 + S1) + (S2 + S3);
        ps += __shfl_xor(ps, 16);
        ps += __shfl_xor(ps, 32);
        lsum = lsum * alpha + ps;
        m = mn;
        o[0] *= alpha;
        o[1] *= alpha;
        #pragma unroll
        for (int kf = 0; kf < 4; ++kf) {
            uint2 pk;
            pk.x = cvt_pk_bf16(p[kf * 4 + 0], p[kf * 4 + 1]);
            pk.y = cvt_pk_bf16(p[kf * 4 + 2], p[kf * 4 + 3]);
            int gr = (kf * 2 + (lg >> 1)) ^ (lr & 7);
            *(uint2*)&Ps[w][lr * 64 + gr * 8 + (lg & 1) * 4] = pk;
        }
        #pragma unroll
        for (int ks = 0; ks < 2; ++ks) {
            bf16x8 pa = *(const bf16x8*)&Ps[w][lr * 64 + (((ks * 4 + lg) ^ (lr & 7))) * 8];
            #pragma unroll
            for (int df = 0; df < 2; ++df)
                o[df] = __builtin_amdgcn_mfma_f32_16x16x32_bf16(va[ks][df], pa, o[df], 0, 0, 0);
        }
        if (kc < 7) {
            int row = tid >> 2, g = tid & 3;
            *(bf16x8*)&Ks[buf ^ 1][(row * 4 + (g ^ ((row >> 1) & 3))) * 8] = knx;
            *(bf16x8*)&Vs[buf ^ 1][tid * 8] = vnx;
        }
        __syncthreads();
    }
    {
        float inv = 1.f / lsum;
        size_t nrow = (size_t)base + q0 + w * 16 + lr;
        #pragma unroll
        for (int df = 0; df < 2; ++df) {
            uint2 ov;
            ov.x = cvt_pk_bf16(o[df][0] * inv, o[df][1] * inv);
            ov.y = cvt_pk_bf16(o[df][2] * inv, o[df][3] * inv);
            *(uint2*)&ao16[nrow * 128 + hd * 32 + df * 16 + lg * 4] = ov;
        }
    }
}

// ---------------- BN3 finalize + apply: h = sc*t + sh; optional fused global-add-pool ----------------
__global__ __launch_bounds__(256) void bn_apply_k(const float* __restrict__ t,
    const float* __restrict__ a3, const float* __restrict__ g3, const float* __restrict__ b3,
    float* __restrict__ h, unsigned short* __restrict__ h16, float* __restrict__ gpool)
{
    __shared__ float sfl[256];
    __shared__ float ps[128];
    int tid = threadIdx.x;
    if (tid < 128) {   // identical formula to the old bn_fin_k
        float mean = a3[tid] * (1.f / N_NODES);
        float var  = a3[128 + tid] * (1.f / N_NODES) - mean * mean;
        float sc   = g3[tid] * rsqrtf(var + 1e-5f);
        sfl[tid] = sc;
        sfl[128 + tid] = b3[tid] - mean * sc;
        if (gpool) ps[tid] = 0.f;
    }
    __syncthreads();
    int idx = blockIdx.x * 256 + tid;
    int cg = (idx & 31) * 4;
    float4 v  = *(const float4*)&t[idx * 4];
    float4 sc = *(const float4*)&sfl[cg];
    float4 sh = *(const float4*)&sfl[128 + cg];
    float4 o;
    o.x = v.x * sc.x + sh.x;
    o.y = v.y * sc.y + sh.y;
    o.z = v.z * sc.z + sh.z;
    o.w = v.w * sc.w + sh.w;
    *(float4*)&h[idx * 4] = o;
    uint2 p;
    p.x = cvt_pk_bf16(o.x, o.y);
    p.y = cvt_pk_bf16(o.z, o.w);
    *(uint2*)&h16[idx * 4] = p;
    if (gpool) {   // block covers 8 nodes of one graph (512 % 8 == 0)
        atomicAdd(&ps[cg + 0], o.x);
        atomicAdd(&ps[cg + 1], o.y);
        atomicAdd(&ps[cg + 2], o.z);
        atomicAdd(&ps[cg + 3], o.w);
        __syncthreads();
        if (tid < 128) atomicAdd(&gpool[(blockIdx.x >> 6) * 128 + tid], ps[tid]);
    }
}

// ---------------- head MLP: [64,128]->64->32->1 ----------------
__global__ __launch_bounds__(256) void head_mlp_k(const float* __restrict__ g,
    const float* __restrict__ w1, const float* __restrict__ b1,
    const float* __restrict__ w2, const float* __restrict__ b2,
    const float* __restrict__ w3, const float* __restrict__ b3,
    float* __restrict__ out)
{
    __shared__ float gs[64 * 128];
    __shared__ float y1[64 * 64];
    __shared__ float y2[64 * 32];
    int tid = threadIdx.x;
    for (int r = 0; r < 32; ++r) gs[r * 256 + tid] = g[r * 256 + tid];
    __syncthreads();
    for (int t = 0; t < 16; ++t) {
        int idx = t * 256 + tid;
        int gi = idx >> 6, c = idx & 63;
        float s = b1[c];
        for (int k = 0; k < 128; ++k) s = fmaf(gs[gi * 128 + k], w1[k * 64 + c], s);
        y1[gi * 64 + c] = fmaxf(s, 0.f);
    }
    __syncthreads();
    for (int t = 0; t < 8; ++t) {
        int idx = t * 256 + tid;
        int gi = idx >> 5, c = idx & 31;
        float s = b2[c];
        for (int k = 0; k < 64; ++k) s = fmaf(y1[gi * 64 + k], w2[k * 32 + c], s);
        y2[gi * 32 + c] = fmaxf(s, 0.f);
    }
    __syncthreads();
    if (tid < 64) {
        float s = b3[0];
        for (int k = 0; k < 32; ++k) s = fmaf(y2[tid * 32 + k], w3[k], s);
        out[tid] = s;
    }
}

extern "C" void kernel_launch(void* const* d_in, const int* in_sizes, int n_in,
                              void* d_out, int out_size, void* d_ws, size_t ws_size,
                              hipStream_t stream)
{
    const int*   x        = (const int*)  d_in[0];
    const float* pe       = (const float*)d_in[1];
    const int*   ei       = (const int*)  d_in[2];
    const int*   eattr    = (const int*)  d_in[3];
    const float* node_emb = (const float*)d_in[5];
    const float* plw      = (const float*)d_in[6];
    const float* plb      = (const float*)d_in[7];
    const float* pe_g     = (const float*)d_in[8];
    const float* pe_b     = (const float*)d_in[9];
    const float* edge_emb = (const float*)d_in[10];
    const float* gw1      = (const float*)d_in[11];
    const float* gb1      = (const float*)d_in[12];
    const float* gw2      = (const float*)d_in[13];
    const float* gb2      = (const float*)d_in[14];
    const float* wqkv     = (const float*)d_in[15];
    const float* bqkv     = (const float*)d_in[16];
    const float* wo       = (const float*)d_in[17];
    const float* bo       = (const float*)d_in[18];
    const float* n1g      = (const float*)d_in[19];
    const float* n1b      = (const float*)d_in[20];
    const float* n2g      = (const float*)d_in[21];
    const float* n2b      = (const float*)d_in[22];
    const float* n3g      = (const float*)d_in[23];
    const float* n3b      = (const float*)d_in[24];
    const float* fw1      = (const float*)d_in[25];
    const float* fb1      = (const float*)d_in[26];
    const float* fw2      = (const float*)d_in[27];
    const float* fb2      = (const float*)d_in[28];
    const float* mw1      = (const float*)d_in[29];
    const float* mb1      = (const float*)d_in[30];
    const float* mw2      = (const float*)d_in[31];
    const float* mb2      = (const float*)d_in[32];
    const float* mw3      = (const float*)d_in[33];
    const float* mb3      = (const float*)d_in[34];

    float* wf  = (float*)d_ws;
    float* Hb  = wf;                                             // h [N,C] f32        [0,1NF)
    unsigned short* Zb16 = (unsigned short*)(wf + (size_t)NF);   // z / attn-out bf16  [1NF,1.5NF)
    float* T1  = wf + 2 * (size_t)NF;                            // t1 / t3 f32        [2NF,3NF)
    unsigned short* QKVb = (unsigned short*)(wf + 3 * (size_t)NF); // qkv bf16 [N,384] [3NF,4.5NF)
    float* T2  = wf + 3 * (size_t)NF;                            // t2 f32 (aliases dead qkv) [3NF,4NF)
    unsigned short* vtg = (unsigned short*)(wf + 4 * (size_t)NF + (size_t)NF / 2); // V^T bf16 [4.5NF,5NF)
    unsigned short* Hb16 = (unsigned short*)(wf + 5 * (size_t)NF); // h bf16 [N,C]     [5NF,5.5NF)
    int* wi     = (int*)(wf + 6 * (size_t)NF);
    int* indptr = wi;                      // N+1
    int* cnt    = wi + 32800;
    int* cnt2   = cnt + N_NODES;
    int* bsum   = cnt2 + N_NODES;          // 128
    int* bpre   = bsum + 128;              // 128
    int* esa    = bpre + 128;              // E packed (src | attr<<16)
    float* st    = (float*)(esa + E_EDGES);
    float* peacc = st;                     // 64
    float* bnacc = st + 64;                // 12*256
    float* gpool = bnacc + 12 * 256;       // 64*128
    short* wT    = (short*)(gpool + 64 * 128);  // 655360 bf16 transposed weights

    const int* srcA = ei;
    const int* dstA = ei + E_EDGES;
    const int LSTR = 163840;

    // zero peacc + bnacc + gpool (gpool now accumulated via atomics)
    hipMemsetAsync(peacc, 0, (64 + 12 * 256 + 64 * 128) * sizeof(float), stream);
    hipMemsetAsync(cnt, 0, 2 * N_NODES * sizeof(int), stream);

    setup_a_k<<<1696, 256, 0, stream>>>(gw1, gw2, wqkv, wo, fw1, fw2, wT, pe, peacc, dstA, cnt);
    bsum_k<<<128, 256, 0, stream>>>(cnt, bsum);
    bscan_k<<<1, 128, 0, stream>>>(bsum, bpre);
    indptr_k<<<128, 256, 0, stream>>>(cnt, bpre, indptr);
    setup_b_k<<<1024 + N_NODES / 2, 256, 0, stream>>>(
        dstA, srcA, eattr, indptr, cnt2, esa,
        x, pe, node_emb, plw, plb, peacc, pe_g, pe_b, Hb, Hb16);

    for (int l = 0; l < L_LAYERS; ++l) {
        const short* gw1t  = wT + (size_t)l * LSTR;
        const short* gw2t  = wT + (size_t)l * LSTR + 16384;
        const short* wqkvt = wT + (size_t)l * LSTR + 32768;
        const short* wot   = wT + (size_t)l * LSTR + 81920;
        const short* fw1t  = wT + (size_t)l * LSTR + 98304;
        const short* fw2t  = wT + (size_t)l * LSTR + 131072;
        const float* lgb1  = gb1 + (size_t)l * 128;
        const float* lgb2  = gb2 + (size_t)l * 128;
        const float* lbqkv = bqkv + (size_t)l * 384;
        const float* lbo   = bo + (size_t)l * 128;
        const float* lfb1  = fb1 + (size_t)l * 256;
        const float* lfb2  = fb2 + (size_t)l * 128;
        float* acc1 = bnacc + (l * 3 + 0) * 256;
        float* acc2 = bnacc + (l * 3 + 1) * 256;
        float* acc3 = bnacc + (l * 3 + 2) * 256;

        gine_gather_k<<<N_NODES / 4, 256, 0, stream>>>(Hb16, esa, indptr, edge_emb, Zb16);
        gine_mlp_k<<<256, 512, 0, stream>>>(
            Zb16, (const unsigned short*)gw1t, lgb1, (const unsigned short*)gw2t, lgb2,
            Hb, T1, acc1);
        mgemm_k<128, 384, 0, 0, false, false, true,  true, true ><<<dim3(3, 256), 256, 0, stream>>>(
            Hb16, nullptr, nullptr, nullptr, (const unsigned short*)wqkvt, lbqkv,
            nullptr, nullptr, nullptr, nullptr, QKVb, nullptr, vtg);
        attn_mfma_k<<<dim3(8, 4, 64), 256, 0, stream>>>(QKVb, vtg, Zb16);
        mgemm_k<128, 128, 0, 1, false, true,  false, true, false><<<dim3(1, 256), 256, 0, stream>>>(
            Zb16, nullptr, nullptr, nullptr, (const unsigned short*)wot, lbo,
            Hb, nullptr, nullptr, nullptr, T2, acc2, nullptr);
        ffn_mlp_k<<<512, 256, 0, stream>>>(
            T1, T2,
            acc1, n1g + l * 128, n1b + l * 128,
            acc2, n2g + l * 128, n2b + l * 128,
            (const unsigned short*)fw1t, lfb1, (const unsigned short*)fw2t, lfb2,
            T1, acc3);
        bn_apply_k<<<NF / 1024, 256, 0, stream>>>(T1, acc3, n3g + l * 128, n3b + l * 128,
                                                  Hb, Hb16, (l == L_LAYERS - 1) ? gpool : nullptr);
    }
    head_mlp_k<<<1, 256, 0, stream>>>(gpool, mw1, mb1, mw2, mb2, mw3, mb3, (float*)d_out);
}